// Round 3
// baseline (673.617 us; speedup 1.0000x reference)
//
#include <hip/hip_runtime.h>
#include <cmath>

// BlockwiseEarlyExitMamba: output depends only on feat[:,31,:] -> compute T=32 tokens.
#define TT 32
#define NTOK 512   // BATCH*TT
#define DM 256
#define DI 512

typedef float vf4 __attribute__((ext_vector_type(4)));

__device__ __forceinline__ float silu_(float x){ return x / (1.f + __expf(-x)); }

#define FMA16() do { \
  acc[0][0] += xv.x*wv.x; acc[0][1] += xv.x*wv.y; acc[0][2] += xv.x*wv.z; acc[0][3] += xv.x*wv.w; \
  acc[1][0] += xv.y*wv.x; acc[1][1] += xv.y*wv.y; acc[1][2] += xv.y*wv.z; acc[1][3] += xv.y*wv.w; \
  acc[2][0] += xv.z*wv.x; acc[2][1] += xv.z*wv.y; acc[2][2] += xv.z*wv.z; acc[2][3] += xv.z*wv.w; \
  acc[3][0] += xv.w*wv.x; acc[3][1] += xv.w*wv.y; acc[3][2] += xv.w*wv.z; acc[3][3] += xv.w*wv.w; \
} while(0)

// ---------------- grid barrier (256 blocks, all resident: 64KB LDS, 1 block/CU) ---
__device__ __forceinline__ void gbar(unsigned* bars, int slot){
  __syncthreads();
  if (threadIdx.x == 0){
    __threadfence();
    __hip_atomic_fetch_add(&bars[slot], 1u, __ATOMIC_ACQ_REL, __HIP_MEMORY_SCOPE_AGENT);
    while (__hip_atomic_load(&bars[slot], __ATOMIC_RELAXED, __HIP_MEMORY_SCOPE_AGENT) < gridDim.x)
      __builtin_amdgcn_s_sleep(2);
    __threadfence();
  }
  __syncthreads();
}

__global__ void k_zero(unsigned* b){ if (threadIdx.x < 64) b[threadIdx.x] = 0u; }

// ---------- frontend: embed -> fusion GEMM (K=136) -> raw s0 (round-2, verified) ---
__global__ __launch_bounds__(128)
void k_front(const float* __restrict__ x,
             const float* __restrict__ ep, const float* __restrict__ ef,
             const float* __restrict__ ed,
             const float* __restrict__ plw, const float* __restrict__ plb,
             const float* __restrict__ piw, const float* __restrict__ pib,
             const float* __restrict__ fw,  const float* __restrict__ fb,
             float* __restrict__ s0)
{
  __shared__ float Xs[136*36];
  __shared__ float Ws[136*68];
  int bb = blockIdx.y;
  int n0 = blockIdx.x*64;
  int tid = threadIdx.x;
  for (int r = 0; r < 34; ++r){
    int idx = r*128 + tid;
    int t = idx & 31, j = idx >> 5;
    const float* xr = x + ((size_t)(bb*1024 + t))*5;
    float v;
    if      (j <  32){ int i = __float2int_rz(xr[0]); i = min(max(i,0),255); v = ep[i*32 + j]; }
    else if (j <  64){ v = xr[1]*plw[j-32] + plb[j-32]; }
    else if (j <  96){ int i = __float2int_rz(xr[2]); i = min(max(i,0),63);  v = ef[i*32 + (j-64)]; }
    else if (j < 128){ v = xr[3]*piw[j-96] + pib[j-96]; }
    else             { int i = __float2int_rz(xr[4]); i = min(max(i,0),1);   v = ed[i*8 + (j-128)]; }
    Xs[j*36 + t] = v;
  }
  {
    int c = tid >> 1, jh = tid & 1;
    const float4* src = (const float4*)(fw + (size_t)(n0 + c)*136 + jh*68);
    #pragma unroll
    for (int q = 0; q < 17; ++q){
      float4 v = src[q];
      int j = jh*68 + q*4;
      Ws[(j+0)*68 + c] = v.x; Ws[(j+1)*68 + c] = v.y;
      Ws[(j+2)*68 + c] = v.z; Ws[(j+3)*68 + c] = v.w;
    }
  }
  __syncthreads();
  int my = tid >> 4, nx = tid & 15;
  float acc[4][4] = {};
  #pragma unroll 4
  for (int k = 0; k < 136; ++k){
    float4 xv = *(const float4*)&Xs[k*36 + my*4];
    float4 wv = *(const float4*)&Ws[k*68 + nx*4];
    FMA16();
  }
  #pragma unroll
  for (int i = 0; i < 4; ++i){
    int t = my*4 + i;
    float4 o;
    o.x = acc[i][0] + fb[n0 + nx*4 + 0];
    o.y = acc[i][1] + fb[n0 + nx*4 + 1];
    o.z = acc[i][2] + fb[n0 + nx*4 + 2];
    o.w = acc[i][3] + fb[n0 + nx*4 + 3];
    *(float4*)&s0[(size_t)(bb*32 + t)*DM + n0 + nx*4] = o;
  }
}

// ---------- token LayerNorm (round-2 k_rln, verified) ------------------------
__global__ __launch_bounds__(64)
void k_rln(const float* __restrict__ p0, const float* __restrict__ g,
           const float* __restrict__ b, float* __restrict__ feat)
{
  int p = blockIdx.x, tid = threadIdx.x;
  size_t off = (size_t)p*DM + tid*4;
  float4 v = *(const float4*)&p0[off];
  float s  = v.x + v.y + v.z + v.w;
  float sq = v.x*v.x + v.y*v.y + v.z*v.z + v.w*v.w;
  #pragma unroll
  for (int o = 1; o < 64; o <<= 1){ s += __shfl_xor(s, o, 64); sq += __shfl_xor(sq, o, 64); }
  float mu = s * (1.f/256.f);
  float var = sq * (1.f/256.f) - mu*mu;
  float r = rsqrtf(var + 1e-5f);
  float4 gg = *(const float4*)&g[tid*4];
  float4 bb = *(const float4*)&b[tid*4];
  float4 o;
  o.x = (v.x-mu)*r*gg.x + bb.x;
  o.y = (v.y-mu)*r*gg.y + bb.y;
  o.z = (v.z-mu)*r*gg.z + bb.z;
  o.w = (v.w-mu)*r*gg.w + bb.w;
  *(float4*)&feat[off] = o;
}

// ---------------- mega kernel: 4 layers + classifier, 20 grid barriers -------
__global__ __launch_bounds__(512, 2)
void k_mega(const float* __restrict__ ipw, const float* __restrict__ cw, const float* __restrict__ cb,
            const float* __restrict__ xpw, const float* __restrict__ dtw, const float* __restrict__ dtb,
            const float* __restrict__ alog, const float* __restrict__ dpr, const float* __restrict__ opw,
            const float* __restrict__ ng, const float* __restrict__ nb,
            const float* __restrict__ w1, const float* __restrict__ b1,
            const float* __restrict__ w2, const float* __restrict__ b2,
            float* __restrict__ feat, float* __restrict__ xc, float* __restrict__ zs,
            float* __restrict__ dtv, float* __restrict__ Bm, float* __restrict__ Cm,
            float* __restrict__ yg, float* __restrict__ parts, float* __restrict__ out,
            unsigned* bars)
{
  __shared__ float lds[16384];   // 64 KB
  int tid = threadIdx.x, bid = blockIdx.x;
  int slot = 0;
  int wvid = tid >> 6, ln = tid & 63;

  for (int ly = 0; ly < 4; ++ly){
    // ================= IP: in_proj GEMM (wave-split-K) + conv/silu fused =====
    {
      int b = bid >> 4, ns = bid & 15, n0 = ns*64;
      const float* wip = ipw + (size_t)ly*262144;
      // stage Xs: feat tile [k 0..255][t 0..31], XOR swizzle on t keyed by k>>4
      {
        int t = tid >> 4, kq = tid & 15;
        const float4* src = (const float4*)(feat + (size_t)(b*32+t)*DM + kq*16);
        int tt = t ^ ((kq & 7) << 2);
        #pragma unroll
        for (int q = 0; q < 4; ++q){
          float4 v = src[q];
          int k = kq*16 + q*4;
          lds[(k+0)*32 + tt] = v.x; lds[(k+1)*32 + tt] = v.y;
          lds[(k+2)*32 + tt] = v.z; lds[(k+3)*32 + tt] = v.w;
        }
      }
      float acc[8][4] = {};
      int ty = ln >> 4, nx = ln & 15;    // out: t = ty*8+i, n = n0 + nx*4+j
      int swz = wvid << 2;
      for (int c = 0; c < 2; ++c){
        __syncthreads();
        { // stage Ws chunk c: [kl 0..127][n 0..63] swizzled on n keyed by kl>>4
          int n = tid >> 3, kh = tid & 7;
          const float4* src = (const float4*)(wip + (size_t)(n0+n)*DM + c*128 + kh*16);
          int nn = n ^ ((kh & 7) << 2);
          float* W = lds + 8192;
          #pragma unroll
          for (int q = 0; q < 4; ++q){
            float4 v = src[q];
            int kl = kh*16 + q*4;
            W[(kl+0)*64 + nn] = v.x; W[(kl+1)*64 + nn] = v.y;
            W[(kl+2)*64 + nn] = v.z; W[(kl+3)*64 + nn] = v.w;
          }
        }
        __syncthreads();
        const float* W = lds + 8192;
        #pragma unroll
        for (int kk = 0; kk < 16; ++kk){
          int kl = wvid*16 + kk;
          int kg = c*128 + kl;
          int a0 = (ty*8) ^ swz;
          vf4 x0 = *(const vf4*)&lds[kg*32 + a0];
          vf4 x1 = *(const vf4*)&lds[kg*32 + (a0 ^ 4)];
          vf4 wv = *(const vf4*)&W[kl*64 + ((nx*4) ^ swz)];
          #pragma unroll
          for (int i = 0; i < 4; ++i){
            #pragma unroll
            for (int j = 0; j < 4; ++j){
              acc[i][j]   += x0[i]*wv[j];
              acc[i+4][j] += x1[i]*wv[j];
            }
          }
        }
      }
      // pairwise cross-wave reduction (3 rounds) in Ws region
      float* P = lds + 8192;
      for (int s = 4; s >= 1; s >>= 1){
        __syncthreads();
        if (wvid >= s && wvid < 2*s){
          float* dst = P + (wvid - s)*2048;
          #pragma unroll
          for (int i = 0; i < 8; ++i) *(vf4*)&dst[i*256 + ln*4] = *(vf4*)&acc[i][0];
        }
        __syncthreads();
        if (wvid < s){
          const float* sp = P + wvid*2048;
          #pragma unroll
          for (int i = 0; i < 8; ++i){
            vf4 v = *(const vf4*)&sp[i*256 + ln*4];
            acc[i][0]+=v[0]; acc[i][1]+=v[1]; acc[i][2]+=v[2]; acc[i][3]+=v[3];
          }
        }
      }
      __syncthreads();
      float* sxz = lds;   // [32][68]
      if (wvid == 0){
        #pragma unroll
        for (int i = 0; i < 8; ++i){
          int t = ty*8 + i;
          *(vf4*)&sxz[t*68 + nx*4] = *(vf4*)&acc[i][0];
        }
      }
      __syncthreads();
      { // conv+silu (x-slices) or silu (z-slices)
        int t = tid >> 4, nn = (tid & 15)*4;
        int p = b*32 + t;
        float4 r;
        if (n0 < 512){
          const float* cwl = cw + (size_t)ly*2048;
          const float* cbl = cb + (size_t)ly*512;
          #pragma unroll
          for (int j = 0; j < 4; ++j){
            int d = n0 + nn + j;
            float4 k4 = *(const float4*)(cwl + (size_t)d*4);
            float a = cbl[d];
            if (t >= 3) a += k4.x * sxz[(t-3)*68 + nn + j];
            if (t >= 2) a += k4.y * sxz[(t-2)*68 + nn + j];
            if (t >= 1) a += k4.z * sxz[(t-1)*68 + nn + j];
            a += k4.w * sxz[t*68 + nn + j];
            ((float*)&r)[j] = silu_(a);
          }
          *(float4*)&xc[(size_t)p*DI + n0 + nn] = r;
        } else {
          int dz = n0 - 512 + nn;
          #pragma unroll
          for (int j = 0; j < 4; ++j) ((float*)&r)[j] = silu_(sxz[t*68 + nn + j]);
          *(float4*)&zs[(size_t)p*DI + dz] = r;
        }
      }
    }
    gbar(bars, slot++);

    // ================= XP: x_proj (8 waves x 6 ch, 2 tokens) + dt softplus ===
    {
      int p0 = bid*2;
      float* sxc = lds;            // [2][512]
      float* sdtr = lds + 1024;    // [2][16]
      {
        int h = tid >> 8, i = tid & 255;
        *(float2*)&sxc[h*512 + i*2] = *(const float2*)&xc[(size_t)(p0+h)*DI + i*2];
      }
      __syncthreads();
      const float* xpl = xpw + (size_t)ly*48*512;
      #pragma unroll
      for (int j = 0; j < 6; ++j){
        int c = wvid*6 + j;
        const float* wr = xpl + (size_t)c*512;
        float pa = 0.f, pb = 0.f;
        #pragma unroll
        for (int q = 0; q < 8; ++q){
          float wv = wr[ln + 64*q];
          pa += wv * sxc[ln + 64*q];
          pb += wv * sxc[512 + ln + 64*q];
        }
        #pragma unroll
        for (int o = 32; o; o >>= 1){ pa += __shfl_down(pa, o, 64); pb += __shfl_down(pb, o, 64); }
        if (ln == 0){
          if (c < 16){ sdtr[c] = pa; sdtr[16 + c] = pb; }
          else if (c < 32){ Bm[(size_t)p0*16 + (c-16)] = pa; Bm[(size_t)(p0+1)*16 + (c-16)] = pb; }
          else            { Cm[(size_t)p0*16 + (c-32)] = pa; Cm[(size_t)(p0+1)*16 + (c-32)] = pb; }
        }
      }
      __syncthreads();
      {
        int d = tid;
        const float4* dwr = (const float4*)(dtw + (size_t)ly*8192 + (size_t)d*16);
        float4 a0 = dwr[0], a1 = dwr[1], a2 = dwr[2], a3 = dwr[3];
        float bsv = dtb[ly*512 + d];
        #pragma unroll
        for (int h = 0; h < 2; ++h){
          const float* sr = sdtr + h*16;
          float a = bsv;
          a += a0.x*sr[0] + a0.y*sr[1] + a0.z*sr[2] + a0.w*sr[3];
          a += a1.x*sr[4] + a1.y*sr[5] + a1.z*sr[6] + a1.w*sr[7];
          a += a2.x*sr[8] + a2.y*sr[9] + a2.z*sr[10]+ a2.w*sr[11];
          a += a3.x*sr[12]+ a3.y*sr[13]+ a3.z*sr[14]+ a3.w*sr[15];
          dtv[(size_t)(p0+h)*DI + d] = fmaxf(a, 0.f) + log1pf(expf(-fabsf(a)));
        }
      }
    }
    gbar(bars, slot++);

    // ================= SC: selective scan (d,n parallel) + D-skip + gate =====
    {
      int b = bid >> 4, ds = bid & 15, d0 = ds*32;
      int dd = tid >> 4, nidx = tid & 15;
      int d = d0 + dd;
      float* sdt = lds;            // [32][34]
      float* sxv = lds + 1088;
      float* szz = lds + 2176;
      float* sB  = lds + 3264;     // [32][18]
      float* sC  = lds + 3840;
      {
        int t = tid >> 4, q = (tid & 15)*2;
        size_t base = (size_t)(b*32 + t)*DI + d0 + q;
        *(float2*)&sdt[t*34 + q] = *(const float2*)&dtv[base];
        *(float2*)&sxv[t*34 + q] = *(const float2*)&xc[base];
        *(float2*)&szz[t*34 + q] = *(const float2*)&zs[base];
        if ((tid & 15) < 8){
          int n2 = (tid & 7)*2;
          *(float2*)&sB[t*18 + n2] = *(const float2*)&Bm[(size_t)(b*32+t)*16 + n2];
          *(float2*)&sC[t*18 + n2] = *(const float2*)&Cm[(size_t)(b*32+t)*16 + n2];
        }
      }
      __syncthreads();
      float A = -expf(alog[(size_t)ly*8192 + (size_t)d*16 + nidx]);
      float Dp = dpr[ly*512 + d];
      float h = 0.f;
      #pragma unroll 4
      for (int t = 0; t < TT; ++t){
        float dt = sdt[t*34 + dd];
        float xv = sxv[t*34 + dd];
        h = __expf(dt*A)*h + (dt*xv)*sB[t*18 + nidx];
        float yv = h * sC[t*18 + nidx];
        #pragma unroll
        for (int o = 8; o; o >>= 1) yv += __shfl_xor(yv, o, 64);
        if (nidx == 0){
          float yo = (yv + Dp*xv) * szz[t*34 + dd];
          yg[(size_t)(b*32+t)*DI + d] = yo;
        }
      }
    }
    gbar(bars, slot++);

    // ================= OP: out_proj GEMM (2-way split-K, wave-split) =========
    {
      int mt = bid >> 4, ns = (bid >> 1) & 7, kz = bid & 1;
      int m0 = mt*32, n0 = ns*32, k0 = kz*256;
      const float* wop = opw + (size_t)ly*131072;
      { // Xs: yg tile [k 0..255][t 0..31]
        int t = tid >> 4, kq = tid & 15;
        const float4* src = (const float4*)(yg + (size_t)(m0+t)*DI + k0 + kq*16);
        int tt = t ^ ((kq & 7) << 2);
        #pragma unroll
        for (int q = 0; q < 4; ++q){
          float4 v = src[q];
          int k = kq*16 + q*4;
          lds[(k+0)*32 + tt] = v.x; lds[(k+1)*32 + tt] = v.y;
          lds[(k+2)*32 + tt] = v.z; lds[(k+3)*32 + tt] = v.w;
        }
      }
      { // Ws: opw tile [k 0..255][n 0..31]
        int n = tid >> 4, kh = tid & 15;
        const float4* src = (const float4*)(wop + (size_t)(n0+n)*DI + k0 + kh*16);
        int nn = n ^ ((kh & 7) << 2);
        float* W = lds + 8192;
        #pragma unroll
        for (int q = 0; q < 4; ++q){
          float4 v = src[q];
          int k = kh*16 + q*4;
          W[(k+0)*32 + nn] = v.x; W[(k+1)*32 + nn] = v.y;
          W[(k+2)*32 + nn] = v.z; W[(k+3)*32 + nn] = v.w;
        }
      }
      __syncthreads();
      int ty = ln >> 3, nx = ln & 7;   // out t = m0+ty*4+i, n = n0+nx*4+j
      float acc[4][4] = {};
      const float* W = lds + 8192;
      #pragma unroll
      for (int kk = 0; kk < 32; ++kk){
        int k = wvid*32 + kk;
        int swz = ((k >> 4) & 7) << 2;
        vf4 xv = *(const vf4*)&lds[k*32 + ((ty*4) ^ swz)];
        vf4 wv = *(const vf4*)&W[k*32 + ((nx*4) ^ swz)];
        #pragma unroll
        for (int i = 0; i < 4; ++i){
          #pragma unroll
          for (int j = 0; j < 4; ++j) acc[i][j] += xv[i]*wv[j];
        }
      }
      float* P = lds + 8192;
      for (int s = 4; s >= 1; s >>= 1){
        __syncthreads();
        if (wvid >= s && wvid < 2*s){
          float* dst = P + (wvid - s)*1024;
          #pragma unroll
          for (int i = 0; i < 4; ++i) *(vf4*)&dst[i*256 + ln*4] = *(vf4*)&acc[i][0];
        }
        __syncthreads();
        if (wvid < s){
          const float* sp = P + wvid*1024;
          #pragma unroll
          for (int i = 0; i < 4; ++i){
            vf4 v = *(const vf4*)&sp[i*256 + ln*4];
            acc[i][0]+=v[0]; acc[i][1]+=v[1]; acc[i][2]+=v[2]; acc[i][3]+=v[3];
          }
        }
      }
      if (wvid == 0){
        #pragma unroll
        for (int i = 0; i < 4; ++i)
          *(vf4*)&parts[(size_t)kz*131072 + (size_t)(m0 + ty*4 + i)*DM + n0 + nx*4] = *(vf4*)&acc[i][0];
      }
    }
    gbar(bars, slot++);

    // ================= RL: sum parts + residual + LayerNorm ==================
    {
      int hh = tid >> 8;
      int p = bid*2 + hh;
      int i = tid & 255;
      size_t off = (size_t)p*DM + i;
      float v = parts[off] + parts[131072 + off] + feat[off];
      float s = v, sq = v*v;
      #pragma unroll
      for (int o = 32; o; o >>= 1){ s += __shfl_xor(s, o, 64); sq += __shfl_xor(sq, o, 64); }
      float* red = lds;
      int ww = (tid >> 6) & 3;
      if ((tid & 63) == 0){ red[hh*8 + ww*2] = s; red[hh*8 + ww*2 + 1] = sq; }
      __syncthreads();
      float S  = red[hh*8+0]+red[hh*8+2]+red[hh*8+4]+red[hh*8+6];
      float SQ = red[hh*8+1]+red[hh*8+3]+red[hh*8+5]+red[hh*8+7];
      float mu = S*(1.f/256.f), var = SQ*(1.f/256.f) - mu*mu;
      float r = rsqrtf(var + 1e-5f);
      feat[off] = (v - mu)*r*ng[i] + nb[i];
    }
    gbar(bars, slot++);
  } // layers

  // ================= CLS: classifier on token 31 ============================
  if (bid < 16){
    int b = bid;
    float* h = lds;          // 256
    float* h1 = lds + 256;   // 128
    const float* fr = feat + (size_t)(b*32 + 31)*DM;
    if (tid < 256) h[tid] = fr[tid];
    __syncthreads();
    if (tid < 128){
      float a = b1[tid];
      const float* wr = w1 + (size_t)tid*256;
      #pragma unroll 8
      for (int j = 0; j < 256; ++j) a += h[j]*wr[j];
      h1[tid] = fmaxf(a, 0.f);
    }
    __syncthreads();
    if (tid < 2){
      float a2 = b2[tid];
      const float* wr2 = w2 + (size_t)tid*128;
      #pragma unroll 8
      for (int j = 0; j < 128; ++j) a2 += h1[j]*wr2[j];
      out[b*2 + tid] = a2;
    }
  }
}

extern "C" void kernel_launch(void* const* d_in, const int* in_sizes, int n_in,
                              void* d_out, int out_size, void* d_ws, size_t ws_size,
                              hipStream_t stream)
{
  const float* x   = (const float*)d_in[0];
  const float* ep  = (const float*)d_in[1];
  const float* ef  = (const float*)d_in[2];
  const float* ed  = (const float*)d_in[3];
  const float* plw = (const float*)d_in[4];
  const float* plb = (const float*)d_in[5];
  const float* piw = (const float*)d_in[6];
  const float* pib = (const float*)d_in[7];
  const float* fw  = (const float*)d_in[8];
  const float* fb  = (const float*)d_in[9];
  const float* tg  = (const float*)d_in[10];
  const float* tb  = (const float*)d_in[11];
  const float* ng  = (const float*)d_in[12];
  const float* nb  = (const float*)d_in[13];
  const float* ipw = (const float*)d_in[14];
  const float* cw  = (const float*)d_in[15];
  const float* cb  = (const float*)d_in[16];
  const float* xpw = (const float*)d_in[17];
  const float* dtw = (const float*)d_in[18];
  const float* dtb = (const float*)d_in[19];
  const float* alog= (const float*)d_in[20];
  const float* dpr = (const float*)d_in[21];
  const float* opw = (const float*)d_in[22];
  const float* w1  = (const float*)d_in[23];
  const float* b1  = (const float*)d_in[24];
  const float* w2  = (const float*)d_in[25];
  const float* b2  = (const float*)d_in[26];
  (void)in_sizes; (void)n_in; (void)out_size; (void)ws_size;

  float* ws    = (float*)d_ws;
  float* feat  = ws;                       // 512*256
  float* xcb   = feat + NTOK*DM;           // 512*512
  float* zsb   = xcb  + NTOK*DI;           // 512*512
  float* dtvb  = zsb  + NTOK*DI;           // 512*512
  float* ygb   = dtvb + NTOK*DI;           // 512*512
  float* Bmb   = ygb  + NTOK*DI;           // 512*16
  float* Cmb   = Bmb  + NTOK*16;           // 512*16
  float* partsb= Cmb  + NTOK*16;           // 2*512*256
  float* s0    = partsb + 2*NTOK*DM;       // 512*256
  unsigned* bars = (unsigned*)(s0 + NTOK*DM);

  k_zero<<<1,64,0,stream>>>(bars);
  k_front<<<dim3(4,16),128,0,stream>>>(x, ep,ef,ed, plw,plb,piw,pib, fw,fb, s0);
  k_rln<<<NTOK,64,0,stream>>>(s0, tg, tb, feat);
  k_mega<<<256,512,0,stream>>>(ipw, cw, cb, xpw, dtw, dtb, alog, dpr, opw,
                               ng, nb, w1, b1, w2, b2,
                               feat, xcb, zsb, dtvb, Bmb, Cmb, ygb, partsb,
                               (float*)d_out, bars);
}

// Round 4
// 622.948 us; speedup vs baseline: 1.0813x; 1.0813x over previous
//
#include <hip/hip_runtime.h>
#include <cmath>

// BlockwiseEarlyExitMamba: output depends only on feat[:,31,:] -> compute T=32 tokens.
#define TT 32
#define NTOK 512   // BATCH*TT
#define DM 256
#define DI 512

typedef float vf4 __attribute__((ext_vector_type(4)));

__device__ __forceinline__ float silu_(float x){ return x / (1.f + __expf(-x)); }

#define FMA16() do { \
  acc[0][0] += xv.x*wv.x; acc[0][1] += xv.x*wv.y; acc[0][2] += xv.x*wv.z; acc[0][3] += xv.x*wv.w; \
  acc[1][0] += xv.y*wv.x; acc[1][1] += xv.y*wv.y; acc[1][2] += xv.y*wv.z; acc[1][3] += xv.y*wv.w; \
  acc[2][0] += xv.z*wv.x; acc[2][1] += xv.z*wv.y; acc[2][2] += xv.z*wv.z; acc[2][3] += xv.z*wv.w; \
  acc[3][0] += xv.w*wv.x; acc[3][1] += xv.w*wv.y; acc[3][2] += xv.w*wv.z; acc[3][3] += xv.w*wv.w; \
} while(0)

// ---- per-batch barrier: 16 blocks, per-block padded flag lines, monotonic epoch ----
// flags layout: u32 flags[16 batch][16 sub][16 pad]  (64B line per block)
__device__ __forceinline__ void bbar(unsigned* flags, int b, int sub, unsigned e){
  __syncthreads();
  if (threadIdx.x == 0){
    __threadfence();
    __hip_atomic_store(&flags[(b*16 + sub)*16], e, __ATOMIC_RELEASE, __HIP_MEMORY_SCOPE_AGENT);
  }
  if (threadIdx.x < 16){
    while (__hip_atomic_load(&flags[(b*16 + threadIdx.x)*16], __ATOMIC_ACQUIRE,
                             __HIP_MEMORY_SCOPE_AGENT) < e)
      __builtin_amdgcn_s_sleep(1);
    __threadfence();
  }
  __syncthreads();
}

__global__ void k_zero(unsigned* f){
  for (int i = 0; i < 8; ++i) f[i*512 + threadIdx.x] = 0u;   // 4096 words
}

// ---------- frontend: embed -> fusion GEMM (K=136) -> raw s0 (verified) ------
__global__ __launch_bounds__(128)
void k_front(const float* __restrict__ x,
             const float* __restrict__ ep, const float* __restrict__ ef,
             const float* __restrict__ ed,
             const float* __restrict__ plw, const float* __restrict__ plb,
             const float* __restrict__ piw, const float* __restrict__ pib,
             const float* __restrict__ fw,  const float* __restrict__ fb,
             float* __restrict__ s0)
{
  __shared__ float Xs[136*36];
  __shared__ float Ws[136*68];
  int bb = blockIdx.y;
  int n0 = blockIdx.x*64;
  int tid = threadIdx.x;
  for (int r = 0; r < 34; ++r){
    int idx = r*128 + tid;
    int t = idx & 31, j = idx >> 5;
    const float* xr = x + ((size_t)(bb*1024 + t))*5;
    float v;
    if      (j <  32){ int i = __float2int_rz(xr[0]); i = min(max(i,0),255); v = ep[i*32 + j]; }
    else if (j <  64){ v = xr[1]*plw[j-32] + plb[j-32]; }
    else if (j <  96){ int i = __float2int_rz(xr[2]); i = min(max(i,0),63);  v = ef[i*32 + (j-64)]; }
    else if (j < 128){ v = xr[3]*piw[j-96] + pib[j-96]; }
    else             { int i = __float2int_rz(xr[4]); i = min(max(i,0),1);   v = ed[i*8 + (j-128)]; }
    Xs[j*36 + t] = v;
  }
  {
    int c = tid >> 1, jh = tid & 1;
    const float4* src = (const float4*)(fw + (size_t)(n0 + c)*136 + jh*68);
    #pragma unroll
    for (int q = 0; q < 17; ++q){
      float4 v = src[q];
      int j = jh*68 + q*4;
      Ws[(j+0)*68 + c] = v.x; Ws[(j+1)*68 + c] = v.y;
      Ws[(j+2)*68 + c] = v.z; Ws[(j+3)*68 + c] = v.w;
    }
  }
  __syncthreads();
  int my = tid >> 4, nx = tid & 15;
  float acc[4][4] = {};
  #pragma unroll 4
  for (int k = 0; k < 136; ++k){
    float4 xv = *(const float4*)&Xs[k*36 + my*4];
    float4 wv = *(const float4*)&Ws[k*68 + nx*4];
    FMA16();
  }
  #pragma unroll
  for (int i = 0; i < 4; ++i){
    int t = my*4 + i;
    float4 o;
    o.x = acc[i][0] + fb[n0 + nx*4 + 0];
    o.y = acc[i][1] + fb[n0 + nx*4 + 1];
    o.z = acc[i][2] + fb[n0 + nx*4 + 2];
    o.w = acc[i][3] + fb[n0 + nx*4 + 3];
    *(float4*)&s0[(size_t)(bb*32 + t)*DM + n0 + nx*4] = o;
  }
}

// ---------- token LayerNorm (verified) ---------------------------------------
__global__ __launch_bounds__(64)
void k_rln(const float* __restrict__ p0, const float* __restrict__ g,
           const float* __restrict__ b, float* __restrict__ feat)
{
  int p = blockIdx.x, tid = threadIdx.x;
  size_t off = (size_t)p*DM + tid*4;
  float4 v = *(const float4*)&p0[off];
  float s  = v.x + v.y + v.z + v.w;
  float sq = v.x*v.x + v.y*v.y + v.z*v.z + v.w*v.w;
  #pragma unroll
  for (int o = 1; o < 64; o <<= 1){ s += __shfl_xor(s, o, 64); sq += __shfl_xor(sq, o, 64); }
  float mu = s * (1.f/256.f);
  float var = sq * (1.f/256.f) - mu*mu;
  float r = rsqrtf(var + 1e-5f);
  float4 gg = *(const float4*)&g[tid*4];
  float4 bb = *(const float4*)&b[tid*4];
  float4 o;
  o.x = (v.x-mu)*r*gg.x + bb.x;
  o.y = (v.y-mu)*r*gg.y + bb.y;
  o.z = (v.z-mu)*r*gg.z + bb.z;
  o.w = (v.w-mu)*r*gg.w + bb.w;
  *(float4*)&feat[off] = o;
}

// ---------------- mega kernel: 4 layers + classifier, per-batch barriers -----
// bid = sub*16 + batch  (batch's 16 blocks share bid%8 -> likely one XCD)
__global__ __launch_bounds__(512, 2)
void k_mega(const float* __restrict__ ipw, const float* __restrict__ cw, const float* __restrict__ cb,
            const float* __restrict__ xpw, const float* __restrict__ dtw, const float* __restrict__ dtb,
            const float* __restrict__ alog, const float* __restrict__ dpr, const float* __restrict__ opw,
            const float* __restrict__ ng, const float* __restrict__ nb,
            const float* __restrict__ w1, const float* __restrict__ b1,
            const float* __restrict__ w2, const float* __restrict__ b2,
            float* __restrict__ feat, float* __restrict__ xc, float* __restrict__ zs,
            float* __restrict__ dtv, float* __restrict__ Bm, float* __restrict__ Cm,
            float* __restrict__ yg, float* __restrict__ parts, float* __restrict__ out,
            unsigned* flags)
{
  __shared__ float lds[16384];   // 64 KB
  int tid = threadIdx.x, bid = blockIdx.x;
  int b = bid & 15, sub = bid >> 4;
  int wvid = tid >> 6, ln = tid & 63;
  unsigned ep_ = 0;

  for (int ly = 0; ly < 4; ++ly){
    // ================= IP: in_proj GEMM (wave-split-K) + conv/silu fused =====
    {
      int n0 = sub*64;
      const float* wip = ipw + (size_t)ly*262144;
      {
        int t = tid >> 4, kq = tid & 15;
        const float4* src = (const float4*)(feat + (size_t)(b*32+t)*DM + kq*16);
        int tt = t ^ ((kq & 7) << 2);
        #pragma unroll
        for (int q = 0; q < 4; ++q){
          float4 v = src[q];
          int k = kq*16 + q*4;
          lds[(k+0)*32 + tt] = v.x; lds[(k+1)*32 + tt] = v.y;
          lds[(k+2)*32 + tt] = v.z; lds[(k+3)*32 + tt] = v.w;
        }
      }
      float acc[8][4] = {};
      int ty = ln >> 4, nx = ln & 15;
      int swz = wvid << 2;
      for (int c = 0; c < 2; ++c){
        __syncthreads();
        {
          int n = tid >> 3, kh = tid & 7;
          const float4* src = (const float4*)(wip + (size_t)(n0+n)*DM + c*128 + kh*16);
          int nn = n ^ ((kh & 7) << 2);
          float* W = lds + 8192;
          #pragma unroll
          for (int q = 0; q < 4; ++q){
            float4 v = src[q];
            int kl = kh*16 + q*4;
            W[(kl+0)*64 + nn] = v.x; W[(kl+1)*64 + nn] = v.y;
            W[(kl+2)*64 + nn] = v.z; W[(kl+3)*64 + nn] = v.w;
          }
        }
        __syncthreads();
        const float* W = lds + 8192;
        #pragma unroll
        for (int kk = 0; kk < 16; ++kk){
          int kl = wvid*16 + kk;
          int kg = c*128 + kl;
          int a0 = (ty*8) ^ swz;
          vf4 x0 = *(const vf4*)&lds[kg*32 + a0];
          vf4 x1 = *(const vf4*)&lds[kg*32 + (a0 ^ 4)];
          vf4 wv = *(const vf4*)&W[kl*64 + ((nx*4) ^ swz)];
          #pragma unroll
          for (int i = 0; i < 4; ++i){
            #pragma unroll
            for (int j = 0; j < 4; ++j){
              acc[i][j]   += x0[i]*wv[j];
              acc[i+4][j] += x1[i]*wv[j];
            }
          }
        }
      }
      float* P = lds + 8192;
      for (int s = 4; s >= 1; s >>= 1){
        __syncthreads();
        if (wvid >= s && wvid < 2*s){
          float* dst = P + (wvid - s)*2048;
          #pragma unroll
          for (int i = 0; i < 8; ++i) *(vf4*)&dst[i*256 + ln*4] = *(vf4*)&acc[i][0];
        }
        __syncthreads();
        if (wvid < s){
          const float* sp = P + wvid*2048;
          #pragma unroll
          for (int i = 0; i < 8; ++i){
            vf4 v = *(const vf4*)&sp[i*256 + ln*4];
            acc[i][0]+=v[0]; acc[i][1]+=v[1]; acc[i][2]+=v[2]; acc[i][3]+=v[3];
          }
        }
      }
      __syncthreads();
      float* sxz = lds;   // [32][68]
      if (wvid == 0){
        #pragma unroll
        for (int i = 0; i < 8; ++i){
          int t = ty*8 + i;
          *(vf4*)&sxz[t*68 + nx*4] = *(vf4*)&acc[i][0];
        }
      }
      __syncthreads();
      {
        int t = tid >> 4, nn = (tid & 15)*4;
        int p = b*32 + t;
        float4 r;
        if (n0 < 512){
          const float* cwl = cw + (size_t)ly*2048;
          const float* cbl = cb + (size_t)ly*512;
          #pragma unroll
          for (int j = 0; j < 4; ++j){
            int d = n0 + nn + j;
            float4 k4 = *(const float4*)(cwl + (size_t)d*4);
            float a = cbl[d];
            if (t >= 3) a += k4.x * sxz[(t-3)*68 + nn + j];
            if (t >= 2) a += k4.y * sxz[(t-2)*68 + nn + j];
            if (t >= 1) a += k4.z * sxz[(t-1)*68 + nn + j];
            a += k4.w * sxz[t*68 + nn + j];
            ((float*)&r)[j] = silu_(a);
          }
          *(float4*)&xc[(size_t)p*DI + n0 + nn] = r;
        } else {
          int dz = n0 - 512 + nn;
          #pragma unroll
          for (int j = 0; j < 4; ++j) ((float*)&r)[j] = silu_(sxz[t*68 + nn + j]);
          *(float4*)&zs[(size_t)p*DI + dz] = r;
        }
      }
    }
    bbar(flags, b, sub, ++ep_);

    // ================= XP: x_proj (8 waves x 6 ch, 2 tokens) + dt softplus ===
    {
      int p0 = b*32 + sub*2;
      float* sxc = lds;
      float* sdtr = lds + 1024;
      {
        int h = tid >> 8, i = tid & 255;
        *(float2*)&sxc[h*512 + i*2] = *(const float2*)&xc[(size_t)(p0+h)*DI + i*2];
      }
      __syncthreads();
      const float* xpl = xpw + (size_t)ly*48*512;
      #pragma unroll
      for (int j = 0; j < 6; ++j){
        int c = wvid*6 + j;
        const float* wr = xpl + (size_t)c*512;
        float pa = 0.f, pb = 0.f;
        #pragma unroll
        for (int q = 0; q < 8; ++q){
          float wv = wr[ln + 64*q];
          pa += wv * sxc[ln + 64*q];
          pb += wv * sxc[512 + ln + 64*q];
        }
        #pragma unroll
        for (int o = 32; o; o >>= 1){ pa += __shfl_down(pa, o, 64); pb += __shfl_down(pb, o, 64); }
        if (ln == 0){
          if (c < 16){ sdtr[c] = pa; sdtr[16 + c] = pb; }
          else if (c < 32){ Bm[(size_t)p0*16 + (c-16)] = pa; Bm[(size_t)(p0+1)*16 + (c-16)] = pb; }
          else            { Cm[(size_t)p0*16 + (c-32)] = pa; Cm[(size_t)(p0+1)*16 + (c-32)] = pb; }
        }
      }
      __syncthreads();
      {
        int d = tid;
        const float4* dwr = (const float4*)(dtw + (size_t)ly*8192 + (size_t)d*16);
        float4 a0 = dwr[0], a1 = dwr[1], a2 = dwr[2], a3 = dwr[3];
        float bsv = dtb[ly*512 + d];
        #pragma unroll
        for (int h = 0; h < 2; ++h){
          const float* sr = sdtr + h*16;
          float a = bsv;
          a += a0.x*sr[0] + a0.y*sr[1] + a0.z*sr[2] + a0.w*sr[3];
          a += a1.x*sr[4] + a1.y*sr[5] + a1.z*sr[6] + a1.w*sr[7];
          a += a2.x*sr[8] + a2.y*sr[9] + a2.z*sr[10]+ a2.w*sr[11];
          a += a3.x*sr[12]+ a3.y*sr[13]+ a3.z*sr[14]+ a3.w*sr[15];
          dtv[(size_t)(p0+h)*DI + d] = fmaxf(a, 0.f) + log1pf(expf(-fabsf(a)));
        }
      }
    }
    bbar(flags, b, sub, ++ep_);

    // ================= SC: selective scan (d,n parallel) + D-skip + gate =====
    {
      int d0 = sub*32;
      int dd = tid >> 4, nidx = tid & 15;
      int d = d0 + dd;
      float* sdt = lds;
      float* sxv = lds + 1088;
      float* szz = lds + 2176;
      float* sB  = lds + 3264;
      float* sC  = lds + 3840;
      {
        int t = tid >> 4, q = (tid & 15)*2;
        size_t base = (size_t)(b*32 + t)*DI + d0 + q;
        *(float2*)&sdt[t*34 + q] = *(const float2*)&dtv[base];
        *(float2*)&sxv[t*34 + q] = *(const float2*)&xc[base];
        *(float2*)&szz[t*34 + q] = *(const float2*)&zs[base];
        if ((tid & 15) < 8){
          int n2 = (tid & 7)*2;
          *(float2*)&sB[t*18 + n2] = *(const float2*)&Bm[(size_t)(b*32+t)*16 + n2];
          *(float2*)&sC[t*18 + n2] = *(const float2*)&Cm[(size_t)(b*32+t)*16 + n2];
        }
      }
      __syncthreads();
      float A = -expf(alog[(size_t)ly*8192 + (size_t)d*16 + nidx]);
      float Dp = dpr[ly*512 + d];
      float h = 0.f;
      #pragma unroll 4
      for (int t = 0; t < TT; ++t){
        float dt = sdt[t*34 + dd];
        float xv = sxv[t*34 + dd];
        h = __expf(dt*A)*h + (dt*xv)*sB[t*18 + nidx];
        float yv = h * sC[t*18 + nidx];
        #pragma unroll
        for (int o = 8; o; o >>= 1) yv += __shfl_xor(yv, o, 64);
        if (nidx == 0){
          float yo = (yv + Dp*xv) * szz[t*34 + dd];
          yg[(size_t)(b*32+t)*DI + d] = yo;
        }
      }
    }
    bbar(flags, b, sub, ++ep_);

    // ================= OP: out_proj GEMM (2-way split-K, wave-split) =========
    {
      int ns = sub >> 1, kz = sub & 1;
      int m0 = b*32, n0 = ns*32, k0 = kz*256;
      const float* wop = opw + (size_t)ly*131072;
      {
        int t = tid >> 4, kq = tid & 15;
        const float4* src = (const float4*)(yg + (size_t)(m0+t)*DI + k0 + kq*16);
        int tt = t ^ ((kq & 7) << 2);
        #pragma unroll
        for (int q = 0; q < 4; ++q){
          float4 v = src[q];
          int k = kq*16 + q*4;
          lds[(k+0)*32 + tt] = v.x; lds[(k+1)*32 + tt] = v.y;
          lds[(k+2)*32 + tt] = v.z; lds[(k+3)*32 + tt] = v.w;
        }
      }
      {
        int n = tid >> 4, kh = tid & 15;
        const float4* src = (const float4*)(wop + (size_t)(n0+n)*DI + k0 + kh*16);
        int nn = n ^ ((kh & 7) << 2);
        float* W = lds + 8192;
        #pragma unroll
        for (int q = 0; q < 4; ++q){
          float4 v = src[q];
          int k = kh*16 + q*4;
          W[(k+0)*32 + nn] = v.x; W[(k+1)*32 + nn] = v.y;
          W[(k+2)*32 + nn] = v.z; W[(k+3)*32 + nn] = v.w;
        }
      }
      __syncthreads();
      int ty = ln >> 3, nx = ln & 7;
      float acc[4][4] = {};
      const float* W = lds + 8192;
      #pragma unroll
      for (int kk = 0; kk < 32; ++kk){
        int k = wvid*32 + kk;
        int swz = ((k >> 4) & 7) << 2;
        vf4 xv = *(const vf4*)&lds[k*32 + ((ty*4) ^ swz)];
        vf4 wv = *(const vf4*)&W[k*32 + ((nx*4) ^ swz)];
        #pragma unroll
        for (int i = 0; i < 4; ++i){
          #pragma unroll
          for (int j = 0; j < 4; ++j) acc[i][j] += xv[i]*wv[j];
        }
      }
      float* P = lds + 8192;
      for (int s = 4; s >= 1; s >>= 1){
        __syncthreads();
        if (wvid >= s && wvid < 2*s){
          float* dst = P + (wvid - s)*1024;
          #pragma unroll
          for (int i = 0; i < 4; ++i) *(vf4*)&dst[i*256 + ln*4] = *(vf4*)&acc[i][0];
        }
        __syncthreads();
        if (wvid < s){
          const float* sp = P + wvid*1024;
          #pragma unroll
          for (int i = 0; i < 4; ++i){
            vf4 v = *(const vf4*)&sp[i*256 + ln*4];
            acc[i][0]+=v[0]; acc[i][1]+=v[1]; acc[i][2]+=v[2]; acc[i][3]+=v[3];
          }
        }
      }
      if (wvid == 0){
        #pragma unroll
        for (int i = 0; i < 4; ++i)
          *(vf4*)&parts[(size_t)kz*131072 + (size_t)(m0 + ty*4 + i)*DM + n0 + nx*4] = *(vf4*)&acc[i][0];
      }
    }
    bbar(flags, b, sub, ++ep_);

    // ================= RL: sum parts + residual + LayerNorm ==================
    {
      int hh = tid >> 8;
      int p = b*32 + sub*2 + hh;
      int i = tid & 255;
      size_t off = (size_t)p*DM + i;
      float v = parts[off] + parts[131072 + off] + feat[off];
      float s = v, sq = v*v;
      #pragma unroll
      for (int o = 32; o; o >>= 1){ s += __shfl_xor(s, o, 64); sq += __shfl_xor(sq, o, 64); }
      float* red = lds;
      int ww = (tid >> 6) & 3;
      if ((tid & 63) == 0){ red[hh*8 + ww*2] = s; red[hh*8 + ww*2 + 1] = sq; }
      __syncthreads();
      float S  = red[hh*8+0]+red[hh*8+2]+red[hh*8+4]+red[hh*8+6];
      float SQ = red[hh*8+1]+red[hh*8+3]+red[hh*8+5]+red[hh*8+7];
      float mu = S*(1.f/256.f), var = SQ*(1.f/256.f) - mu*mu;
      float r = rsqrtf(var + 1e-5f);
      feat[off] = (v - mu)*r*ng[i] + nb[i];
    }
    bbar(flags, b, sub, ++ep_);
  } // layers

  // ================= CLS: classifier on token 31 (sub==0 blocks) ============
  if (sub == 0){
    float* h = lds;
    float* h1 = lds + 256;
    const float* fr = feat + (size_t)(b*32 + 31)*DM;
    if (tid < 256) h[tid] = fr[tid];
    __syncthreads();
    if (tid < 128){
      float a = b1[tid];
      const float* wr = w1 + (size_t)tid*256;
      #pragma unroll 8
      for (int j = 0; j < 256; ++j) a += h[j]*wr[j];
      h1[tid] = fmaxf(a, 0.f);
    }
    __syncthreads();
    if (tid < 2){
      float a2 = b2[tid];
      const float* wr2 = w2 + (size_t)tid*128;
      #pragma unroll 8
      for (int j = 0; j < 128; ++j) a2 += h1[j]*wr2[j];
      out[b*2 + tid] = a2;
    }
  }
}

extern "C" void kernel_launch(void* const* d_in, const int* in_sizes, int n_in,
                              void* d_out, int out_size, void* d_ws, size_t ws_size,
                              hipStream_t stream)
{
  const float* x   = (const float*)d_in[0];
  const float* ep  = (const float*)d_in[1];
  const float* ef  = (const float*)d_in[2];
  const float* ed  = (const float*)d_in[3];
  const float* plw = (const float*)d_in[4];
  const float* plb = (const float*)d_in[5];
  const float* piw = (const float*)d_in[6];
  const float* pib = (const float*)d_in[7];
  const float* fw  = (const float*)d_in[8];
  const float* fb  = (const float*)d_in[9];
  const float* tg  = (const float*)d_in[10];
  const float* tb  = (const float*)d_in[11];
  const float* ng  = (const float*)d_in[12];
  const float* nb  = (const float*)d_in[13];
  const float* ipw = (const float*)d_in[14];
  const float* cw  = (const float*)d_in[15];
  const float* cb  = (const float*)d_in[16];
  const float* xpw = (const float*)d_in[17];
  const float* dtw = (const float*)d_in[18];
  const float* dtb = (const float*)d_in[19];
  const float* alog= (const float*)d_in[20];
  const float* dpr = (const float*)d_in[21];
  const float* opw = (const float*)d_in[22];
  const float* w1  = (const float*)d_in[23];
  const float* b1  = (const float*)d_in[24];
  const float* w2  = (const float*)d_in[25];
  const float* b2  = (const float*)d_in[26];
  (void)in_sizes; (void)n_in; (void)out_size; (void)ws_size;

  float* ws    = (float*)d_ws;
  float* feat  = ws;                       // 512*256
  float* xcb   = feat + NTOK*DM;           // 512*512
  float* zsb   = xcb  + NTOK*DI;           // 512*512
  float* dtvb  = zsb  + NTOK*DI;           // 512*512
  float* ygb   = dtvb + NTOK*DI;           // 512*512
  float* Bmb   = ygb  + NTOK*DI;           // 512*16
  float* Cmb   = Bmb  + NTOK*16;           // 512*16
  float* partsb= Cmb  + NTOK*16;           // 2*512*256
  float* s0    = partsb + 2*NTOK*DM;       // 512*256
  unsigned* flags = (unsigned*)(s0 + NTOK*DM);   // 4096 u32

  k_zero<<<1,512,0,stream>>>(flags);
  k_front<<<dim3(4,16),128,0,stream>>>(x, ep,ef,ed, plw,plb,piw,pib, fw,fb, s0);
  k_rln<<<NTOK,64,0,stream>>>(s0, tg, tb, feat);
  k_mega<<<256,512,0,stream>>>(ipw, cw, cb, xpw, dtw, dtb, alog, dpr, opw,
                               ng, nb, w1, b1, w2, b2,
                               feat, xcb, zsb, dtvb, Bmb, Cmb, ygb, partsb,
                               (float*)d_out, flags);
}

// Round 5
// 317.442 us; speedup vs baseline: 2.1220x; 1.9624x over previous
//
#include <hip/hip_runtime.h>
#include <cmath>

// BlockwiseEarlyExitMamba: output depends only on feat[:,31,:] -> compute T=32 tokens.
#define TT 32
#define NTOK 512   // BATCH*TT
#define DM 256
#define DI 512

typedef float vf4 __attribute__((ext_vector_type(4)));

__device__ __forceinline__ float silu_(float x){ return x / (1.f + __expf(-x)); }

// coherent (LLC-level) scalar access: compiles to global_load/store sc0 sc1,
// NO buffer_wbl2/buffer_inv (that was the round-3/4 killer).
__device__ __forceinline__ void stc(float* p, float v){
  __hip_atomic_store(p, v, __ATOMIC_RELAXED, __HIP_MEMORY_SCOPE_AGENT);
}
__device__ __forceinline__ float ldc(const float* p){
  return __hip_atomic_load(p, __ATOMIC_RELAXED, __HIP_MEMORY_SCOPE_AGENT);
}

#define FMA16() do { \
  acc[0][0] += xv.x*wv.x; acc[0][1] += xv.x*wv.y; acc[0][2] += xv.x*wv.z; acc[0][3] += xv.x*wv.w; \
  acc[1][0] += xv.y*wv.x; acc[1][1] += xv.y*wv.y; acc[1][2] += xv.y*wv.z; acc[1][3] += xv.y*wv.w; \
  acc[2][0] += xv.z*wv.x; acc[2][1] += xv.z*wv.y; acc[2][2] += xv.z*wv.z; acc[2][3] += xv.z*wv.w; \
  acc[3][0] += xv.w*wv.x; acc[3][1] += xv.w*wv.y; acc[3][2] += xv.w*wv.z; acc[3][3] += xv.w*wv.w; \
} while(0)

// ---- per-batch barrier: fence-free. __syncthreads() drains vmcnt(0) for all
// waves (sc1 stores are at LLC); one relaxed flag store; relaxed poll. --------
__device__ __forceinline__ void bbar(unsigned* flags, int b, int sub, unsigned e){
  __syncthreads();
  if (threadIdx.x == 0){
    asm volatile("s_waitcnt vmcnt(0)" ::: "memory");
    __hip_atomic_store(&flags[(b*16 + sub)*16], e, __ATOMIC_RELAXED, __HIP_MEMORY_SCOPE_AGENT);
  }
  if (threadIdx.x < 16){
    while (__hip_atomic_load(&flags[(b*16 + (int)threadIdx.x)*16], __ATOMIC_RELAXED,
                             __HIP_MEMORY_SCOPE_AGENT) < e)
      __builtin_amdgcn_s_sleep(2);
  }
  __syncthreads();
}

__global__ void k_zero(unsigned* f){
  for (int i = 0; i < 8; ++i) f[i*512 + threadIdx.x] = 0u;   // 4096 words
}

// ---------- frontend: embed -> fusion GEMM (K=136) -> raw s0 (verified) ------
__global__ __launch_bounds__(128)
void k_front(const float* __restrict__ x,
             const float* __restrict__ ep, const float* __restrict__ ef,
             const float* __restrict__ ed,
             const float* __restrict__ plw, const float* __restrict__ plb,
             const float* __restrict__ piw, const float* __restrict__ pib,
             const float* __restrict__ fw,  const float* __restrict__ fb,
             float* __restrict__ s0)
{
  __shared__ float Xs[136*36];
  __shared__ float Ws[136*68];
  int bb = blockIdx.y;
  int n0 = blockIdx.x*64;
  int tid = threadIdx.x;
  for (int r = 0; r < 34; ++r){
    int idx = r*128 + tid;
    int t = idx & 31, j = idx >> 5;
    const float* xr = x + ((size_t)(bb*1024 + t))*5;
    float v;
    if      (j <  32){ int i = __float2int_rz(xr[0]); i = min(max(i,0),255); v = ep[i*32 + j]; }
    else if (j <  64){ v = xr[1]*plw[j-32] + plb[j-32]; }
    else if (j <  96){ int i = __float2int_rz(xr[2]); i = min(max(i,0),63);  v = ef[i*32 + (j-64)]; }
    else if (j < 128){ v = xr[3]*piw[j-96] + pib[j-96]; }
    else             { int i = __float2int_rz(xr[4]); i = min(max(i,0),1);   v = ed[i*8 + (j-128)]; }
    Xs[j*36 + t] = v;
  }
  {
    int c = tid >> 1, jh = tid & 1;
    const float4* src = (const float4*)(fw + (size_t)(n0 + c)*136 + jh*68);
    #pragma unroll
    for (int q = 0; q < 17; ++q){
      float4 v = src[q];
      int j = jh*68 + q*4;
      Ws[(j+0)*68 + c] = v.x; Ws[(j+1)*68 + c] = v.y;
      Ws[(j+2)*68 + c] = v.z; Ws[(j+3)*68 + c] = v.w;
    }
  }
  __syncthreads();
  int my = tid >> 4, nx = tid & 15;
  float acc[4][4] = {};
  #pragma unroll 4
  for (int k = 0; k < 136; ++k){
    float4 xv = *(const float4*)&Xs[k*36 + my*4];
    float4 wv = *(const float4*)&Ws[k*68 + nx*4];
    FMA16();
  }
  #pragma unroll
  for (int i = 0; i < 4; ++i){
    int t = my*4 + i;
    float4 o;
    o.x = acc[i][0] + fb[n0 + nx*4 + 0];
    o.y = acc[i][1] + fb[n0 + nx*4 + 1];
    o.z = acc[i][2] + fb[n0 + nx*4 + 2];
    o.w = acc[i][3] + fb[n0 + nx*4 + 3];
    *(float4*)&s0[(size_t)(bb*32 + t)*DM + n0 + nx*4] = o;
  }
}

// ---------- token LayerNorm (verified) ---------------------------------------
__global__ __launch_bounds__(64)
void k_rln(const float* __restrict__ p0, const float* __restrict__ g,
           const float* __restrict__ b, float* __restrict__ feat)
{
  int p = blockIdx.x, tid = threadIdx.x;
  size_t off = (size_t)p*DM + tid*4;
  float4 v = *(const float4*)&p0[off];
  float s  = v.x + v.y + v.z + v.w;
  float sq = v.x*v.x + v.y*v.y + v.z*v.z + v.w*v.w;
  #pragma unroll
  for (int o = 1; o < 64; o <<= 1){ s += __shfl_xor(s, o, 64); sq += __shfl_xor(sq, o, 64); }
  float mu = s * (1.f/256.f);
  float var = sq * (1.f/256.f) - mu*mu;
  float r = rsqrtf(var + 1e-5f);
  float4 gg = *(const float4*)&g[tid*4];
  float4 bb = *(const float4*)&b[tid*4];
  float4 o;
  o.x = (v.x-mu)*r*gg.x + bb.x;
  o.y = (v.y-mu)*r*gg.y + bb.y;
  o.z = (v.z-mu)*r*gg.z + bb.z;
  o.w = (v.w-mu)*r*gg.w + bb.w;
  *(float4*)&feat[off] = o;
}

// ---------------- mega kernel: 4 layers + classifier, per-batch barriers -----
// bid = sub*16 + batch
__global__ __launch_bounds__(512, 2)
void k_mega(const float* __restrict__ ipw, const float* __restrict__ cw, const float* __restrict__ cb,
            const float* __restrict__ xpw, const float* __restrict__ dtw, const float* __restrict__ dtb,
            const float* __restrict__ alog, const float* __restrict__ dpr, const float* __restrict__ opw,
            const float* __restrict__ ng, const float* __restrict__ nb,
            const float* __restrict__ w1, const float* __restrict__ b1,
            const float* __restrict__ w2, const float* __restrict__ b2,
            float* __restrict__ feat, float* __restrict__ xc, float* __restrict__ zs,
            float* __restrict__ dtv, float* __restrict__ Bm, float* __restrict__ Cm,
            float* __restrict__ yg, float* __restrict__ parts, float* __restrict__ out,
            unsigned* flags)
{
  __shared__ float lds[16384];   // 64 KB
  int tid = threadIdx.x, bid = blockIdx.x;
  int b = bid & 15, sub = bid >> 4;
  int wvid = tid >> 6, ln = tid & 63;
  unsigned ep_ = 0;

  for (int ly = 0; ly < 4; ++ly){
    // ================= IP: in_proj GEMM (wave-split-K) + conv/silu fused =====
    {
      int n0 = sub*64;
      const float* wip = ipw + (size_t)ly*262144;
      {
        int t = tid >> 4, kq = tid & 15;
        const float* src = feat + (size_t)(b*32+t)*DM + kq*16;
        int tt = t ^ ((kq & 7) << 2);
        #pragma unroll
        for (int q = 0; q < 4; ++q){
          int k = kq*16 + q*4;
          lds[(k+0)*32 + tt] = ldc(src + q*4 + 0);
          lds[(k+1)*32 + tt] = ldc(src + q*4 + 1);
          lds[(k+2)*32 + tt] = ldc(src + q*4 + 2);
          lds[(k+3)*32 + tt] = ldc(src + q*4 + 3);
        }
      }
      float acc[8][4] = {};
      int ty = ln >> 4, nx = ln & 15;
      int swz = wvid << 2;
      for (int c = 0; c < 2; ++c){
        __syncthreads();
        {
          int n = tid >> 3, kh = tid & 7;
          const float4* src = (const float4*)(wip + (size_t)(n0+n)*DM + c*128 + kh*16);
          int nn = n ^ ((kh & 7) << 2);
          float* W = lds + 8192;
          #pragma unroll
          for (int q = 0; q < 4; ++q){
            float4 v = src[q];
            int kl = kh*16 + q*4;
            W[(kl+0)*64 + nn] = v.x; W[(kl+1)*64 + nn] = v.y;
            W[(kl+2)*64 + nn] = v.z; W[(kl+3)*64 + nn] = v.w;
          }
        }
        __syncthreads();
        const float* W = lds + 8192;
        #pragma unroll
        for (int kk = 0; kk < 16; ++kk){
          int kl = wvid*16 + kk;
          int kg = c*128 + kl;
          int a0 = (ty*8) ^ swz;
          vf4 x0 = *(const vf4*)&lds[kg*32 + a0];
          vf4 x1 = *(const vf4*)&lds[kg*32 + (a0 ^ 4)];
          vf4 wv = *(const vf4*)&W[kl*64 + ((nx*4) ^ swz)];
          #pragma unroll
          for (int i = 0; i < 4; ++i){
            #pragma unroll
            for (int j = 0; j < 4; ++j){
              acc[i][j]   += x0[i]*wv[j];
              acc[i+4][j] += x1[i]*wv[j];
            }
          }
        }
      }
      float* P = lds + 8192;
      for (int s = 4; s >= 1; s >>= 1){
        __syncthreads();
        if (wvid >= s && wvid < 2*s){
          float* dst = P + (wvid - s)*2048;
          #pragma unroll
          for (int i = 0; i < 8; ++i) *(vf4*)&dst[i*256 + ln*4] = *(vf4*)&acc[i][0];
        }
        __syncthreads();
        if (wvid < s){
          const float* sp = P + wvid*2048;
          #pragma unroll
          for (int i = 0; i < 8; ++i){
            vf4 v = *(const vf4*)&sp[i*256 + ln*4];
            acc[i][0]+=v[0]; acc[i][1]+=v[1]; acc[i][2]+=v[2]; acc[i][3]+=v[3];
          }
        }
      }
      __syncthreads();
      float* sxz = lds;   // [32][68]
      if (wvid == 0){
        #pragma unroll
        for (int i = 0; i < 8; ++i){
          int t = ty*8 + i;
          *(vf4*)&sxz[t*68 + nx*4] = *(vf4*)&acc[i][0];
        }
      }
      __syncthreads();
      {
        int t = tid >> 4, nn = (tid & 15)*4;
        int p = b*32 + t;
        float rr[4];
        if (n0 < 512){
          const float* cwl = cw + (size_t)ly*2048;
          const float* cbl = cb + (size_t)ly*512;
          #pragma unroll
          for (int j = 0; j < 4; ++j){
            int d = n0 + nn + j;
            float4 k4 = *(const float4*)(cwl + (size_t)d*4);
            float a = cbl[d];
            if (t >= 3) a += k4.x * sxz[(t-3)*68 + nn + j];
            if (t >= 2) a += k4.y * sxz[(t-2)*68 + nn + j];
            if (t >= 1) a += k4.z * sxz[(t-1)*68 + nn + j];
            a += k4.w * sxz[t*68 + nn + j];
            rr[j] = silu_(a);
          }
          size_t xo = (size_t)p*DI + n0 + nn;
          stc(&xc[xo+0], rr[0]); stc(&xc[xo+1], rr[1]);
          stc(&xc[xo+2], rr[2]); stc(&xc[xo+3], rr[3]);
        } else {
          int dz = n0 - 512 + nn;
          #pragma unroll
          for (int j = 0; j < 4; ++j) rr[j] = silu_(sxz[t*68 + nn + j]);
          size_t zo = (size_t)p*DI + dz;
          stc(&zs[zo+0], rr[0]); stc(&zs[zo+1], rr[1]);
          stc(&zs[zo+2], rr[2]); stc(&zs[zo+3], rr[3]);
        }
      }
    }
    bbar(flags, b, sub, ++ep_);

    // ================= XP: x_proj (8 waves x 6 ch, 2 tokens) + dt softplus ===
    {
      int p0 = b*32 + sub*2;
      float* sxc = lds;
      float* sdtr = lds + 1024;
      {
        int h = tid >> 8, i = tid & 255;
        const float* src = xc + (size_t)(p0+h)*DI + i*2;
        sxc[h*512 + i*2]     = ldc(src);
        sxc[h*512 + i*2 + 1] = ldc(src + 1);
      }
      __syncthreads();
      const float* xpl = xpw + (size_t)ly*48*512;
      #pragma unroll
      for (int j = 0; j < 6; ++j){
        int c = wvid*6 + j;
        const float* wr = xpl + (size_t)c*512;
        float pa = 0.f, pb = 0.f;
        #pragma unroll
        for (int q = 0; q < 8; ++q){
          float wv = wr[ln + 64*q];
          pa += wv * sxc[ln + 64*q];
          pb += wv * sxc[512 + ln + 64*q];
        }
        #pragma unroll
        for (int o = 32; o; o >>= 1){ pa += __shfl_down(pa, o, 64); pb += __shfl_down(pb, o, 64); }
        if (ln == 0){
          if (c < 16){ sdtr[c] = pa; sdtr[16 + c] = pb; }
          else if (c < 32){ stc(&Bm[(size_t)p0*16 + (c-16)], pa); stc(&Bm[(size_t)(p0+1)*16 + (c-16)], pb); }
          else            { stc(&Cm[(size_t)p0*16 + (c-32)], pa); stc(&Cm[(size_t)(p0+1)*16 + (c-32)], pb); }
        }
      }
      __syncthreads();
      {
        int d = tid;
        const float4* dwr = (const float4*)(dtw + (size_t)ly*8192 + (size_t)d*16);
        float4 a0 = dwr[0], a1 = dwr[1], a2 = dwr[2], a3 = dwr[3];
        float bsv = dtb[ly*512 + d];
        #pragma unroll
        for (int h = 0; h < 2; ++h){
          const float* sr = sdtr + h*16;
          float a = bsv;
          a += a0.x*sr[0] + a0.y*sr[1] + a0.z*sr[2] + a0.w*sr[3];
          a += a1.x*sr[4] + a1.y*sr[5] + a1.z*sr[6] + a1.w*sr[7];
          a += a2.x*sr[8] + a2.y*sr[9] + a2.z*sr[10]+ a2.w*sr[11];
          a += a3.x*sr[12]+ a3.y*sr[13]+ a3.z*sr[14]+ a3.w*sr[15];
          stc(&dtv[(size_t)(p0+h)*DI + d], fmaxf(a, 0.f) + log1pf(expf(-fabsf(a))));
        }
      }
    }
    bbar(flags, b, sub, ++ep_);

    // ================= SC: selective scan (d,n parallel) + D-skip + gate =====
    {
      int d0 = sub*32;
      int dd = tid >> 4, nidx = tid & 15;
      int d = d0 + dd;
      float* sdt = lds;
      float* sxv = lds + 1088;
      float* szz = lds + 2176;
      float* sB  = lds + 3264;
      float* sC  = lds + 3840;
      {
        int t = tid >> 4, q = (tid & 15)*2;
        size_t base = (size_t)(b*32 + t)*DI + d0 + q;
        sdt[t*34 + q]   = ldc(&dtv[base]);  sdt[t*34 + q+1] = ldc(&dtv[base+1]);
        sxv[t*34 + q]   = ldc(&xc[base]);   sxv[t*34 + q+1] = ldc(&xc[base+1]);
        szz[t*34 + q]   = ldc(&zs[base]);   szz[t*34 + q+1] = ldc(&zs[base+1]);
        if ((tid & 15) < 8){
          int n2 = (tid & 7)*2;
          size_t bb_ = (size_t)(b*32+t)*16 + n2;
          sB[t*18 + n2] = ldc(&Bm[bb_]);  sB[t*18 + n2+1] = ldc(&Bm[bb_+1]);
          sC[t*18 + n2] = ldc(&Cm[bb_]);  sC[t*18 + n2+1] = ldc(&Cm[bb_+1]);
        }
      }
      __syncthreads();
      float A = -expf(alog[(size_t)ly*8192 + (size_t)d*16 + nidx]);
      float Dp = dpr[ly*512 + d];
      float h = 0.f;
      #pragma unroll 4
      for (int t = 0; t < TT; ++t){
        float dt = sdt[t*34 + dd];
        float xv = sxv[t*34 + dd];
        h = __expf(dt*A)*h + (dt*xv)*sB[t*18 + nidx];
        float yv = h * sC[t*18 + nidx];
        #pragma unroll
        for (int o = 8; o; o >>= 1) yv += __shfl_xor(yv, o, 64);
        if (nidx == 0){
          float yo = (yv + Dp*xv) * szz[t*34 + dd];
          stc(&yg[(size_t)(b*32+t)*DI + d], yo);
        }
      }
    }
    bbar(flags, b, sub, ++ep_);

    // ================= OP: out_proj GEMM (2-way split-K, wave-split) =========
    {
      int ns = sub >> 1, kz = sub & 1;
      int m0 = b*32, n0 = ns*32, k0 = kz*256;
      const float* wop = opw + (size_t)ly*131072;
      {
        int t = tid >> 4, kq = tid & 15;
        const float* src = yg + (size_t)(m0+t)*DI + k0 + kq*16;
        int tt = t ^ ((kq & 7) << 2);
        #pragma unroll
        for (int q = 0; q < 4; ++q){
          int k = kq*16 + q*4;
          lds[(k+0)*32 + tt] = ldc(src + q*4 + 0);
          lds[(k+1)*32 + tt] = ldc(src + q*4 + 1);
          lds[(k+2)*32 + tt] = ldc(src + q*4 + 2);
          lds[(k+3)*32 + tt] = ldc(src + q*4 + 3);
        }
      }
      {
        int n = tid >> 4, kh = tid & 15;
        const float4* src = (const float4*)(wop + (size_t)(n0+n)*DI + k0 + kh*16);
        int nn = n ^ ((kh & 7) << 2);
        float* W = lds + 8192;
        #pragma unroll
        for (int q = 0; q < 4; ++q){
          float4 v = src[q];
          int k = kh*16 + q*4;
          W[(k+0)*32 + nn] = v.x; W[(k+1)*32 + nn] = v.y;
          W[(k+2)*32 + nn] = v.z; W[(k+3)*32 + nn] = v.w;
        }
      }
      __syncthreads();
      int ty = ln >> 3, nx = ln & 7;
      float acc[4][4] = {};
      const float* W = lds + 8192;
      #pragma unroll
      for (int kk = 0; kk < 32; ++kk){
        int k = wvid*32 + kk;
        int swz = ((k >> 4) & 7) << 2;
        vf4 xv = *(const vf4*)&lds[k*32 + ((ty*4) ^ swz)];
        vf4 wv = *(const vf4*)&W[k*32 + ((nx*4) ^ swz)];
        #pragma unroll
        for (int i = 0; i < 4; ++i){
          #pragma unroll
          for (int j = 0; j < 4; ++j) acc[i][j] += xv[i]*wv[j];
        }
      }
      float* P = lds + 8192;
      for (int s = 4; s >= 1; s >>= 1){
        __syncthreads();
        if (wvid >= s && wvid < 2*s){
          float* dst = P + (wvid - s)*1024;
          #pragma unroll
          for (int i = 0; i < 4; ++i) *(vf4*)&dst[i*256 + ln*4] = *(vf4*)&acc[i][0];
        }
        __syncthreads();
        if (wvid < s){
          const float* sp = P + wvid*1024;
          #pragma unroll
          for (int i = 0; i < 4; ++i){
            vf4 v = *(const vf4*)&sp[i*256 + ln*4];
            acc[i][0]+=v[0]; acc[i][1]+=v[1]; acc[i][2]+=v[2]; acc[i][3]+=v[3];
          }
        }
      }
      if (wvid == 0){
        #pragma unroll
        for (int i = 0; i < 4; ++i){
          size_t po = (size_t)kz*131072 + (size_t)(m0 + ty*4 + i)*DM + n0 + nx*4;
          stc(&parts[po+0], acc[i][0]); stc(&parts[po+1], acc[i][1]);
          stc(&parts[po+2], acc[i][2]); stc(&parts[po+3], acc[i][3]);
        }
      }
    }
    bbar(flags, b, sub, ++ep_);

    // ================= RL: sum parts + residual + LayerNorm ==================
    {
      int hh = tid >> 8;
      int p = b*32 + sub*2 + hh;
      int i = tid & 255;
      size_t off = (size_t)p*DM + i;
      float v = ldc(&parts[off]) + ldc(&parts[131072 + off]) + ldc(&feat[off]);
      float s = v, sq = v*v;
      #pragma unroll
      for (int o = 32; o; o >>= 1){ s += __shfl_xor(s, o, 64); sq += __shfl_xor(sq, o, 64); }
      float* red = lds;
      int ww = (tid >> 6) & 3;
      if ((tid & 63) == 0){ red[hh*8 + ww*2] = s; red[hh*8 + ww*2 + 1] = sq; }
      __syncthreads();
      float S  = red[hh*8+0]+red[hh*8+2]+red[hh*8+4]+red[hh*8+6];
      float SQ = red[hh*8+1]+red[hh*8+3]+red[hh*8+5]+red[hh*8+7];
      float mu = S*(1.f/256.f), var = SQ*(1.f/256.f) - mu*mu;
      float r = rsqrtf(var + 1e-5f);
      stc(&feat[off], (v - mu)*r*ng[i] + nb[i]);
    }
    bbar(flags, b, sub, ++ep_);
  } // layers

  // ================= CLS: classifier on token 31 (sub==0 blocks) ============
  if (sub == 0){
    float* h = lds;
    float* h1 = lds + 256;
    const float* fr = feat + (size_t)(b*32 + 31)*DM;
    if (tid < 256) h[tid] = ldc(fr + tid);
    __syncthreads();
    if (tid < 128){
      float a = b1[tid];
      const float* wr = w1 + (size_t)tid*256;
      #pragma unroll 8
      for (int j = 0; j < 256; ++j) a += h[j]*wr[j];
      h1[tid] = fmaxf(a, 0.f);
    }
    __syncthreads();
    if (tid < 2){
      float a2 = b2[tid];
      const float* wr2 = w2 + (size_t)tid*128;
      #pragma unroll 8
      for (int j = 0; j < 128; ++j) a2 += h1[j]*wr2[j];
      out[b*2 + tid] = a2;
    }
  }
}

extern "C" void kernel_launch(void* const* d_in, const int* in_sizes, int n_in,
                              void* d_out, int out_size, void* d_ws, size_t ws_size,
                              hipStream_t stream)
{
  const float* x   = (const float*)d_in[0];
  const float* ep  = (const float*)d_in[1];
  const float* ef  = (const float*)d_in[2];
  const float* ed  = (const float*)d_in[3];
  const float* plw = (const float*)d_in[4];
  const float* plb = (const float*)d_in[5];
  const float* piw = (const float*)d_in[6];
  const float* pib = (const float*)d_in[7];
  const float* fw  = (const float*)d_in[8];
  const float* fb  = (const float*)d_in[9];
  const float* tg  = (const float*)d_in[10];
  const float* tb  = (const float*)d_in[11];
  const float* ng  = (const float*)d_in[12];
  const float* nb  = (const float*)d_in[13];
  const float* ipw = (const float*)d_in[14];
  const float* cw  = (const float*)d_in[15];
  const float* cb  = (const float*)d_in[16];
  const float* xpw = (const float*)d_in[17];
  const float* dtw = (const float*)d_in[18];
  const float* dtb = (const float*)d_in[19];
  const float* alog= (const float*)d_in[20];
  const float* dpr = (const float*)d_in[21];
  const float* opw = (const float*)d_in[22];
  const float* w1  = (const float*)d_in[23];
  const float* b1  = (const float*)d_in[24];
  const float* w2  = (const float*)d_in[25];
  const float* b2  = (const float*)d_in[26];
  (void)in_sizes; (void)n_in; (void)out_size; (void)ws_size;

  float* ws    = (float*)d_ws;
  float* feat  = ws;                       // 512*256
  float* xcb   = feat + NTOK*DM;           // 512*512
  float* zsb   = xcb  + NTOK*DI;           // 512*512
  float* dtvb  = zsb  + NTOK*DI;           // 512*512
  float* ygb   = dtvb + NTOK*DI;           // 512*512
  float* Bmb   = ygb  + NTOK*DI;           // 512*16
  float* Cmb   = Bmb  + NTOK*16;           // 512*16
  float* partsb= Cmb  + NTOK*16;           // 2*512*256
  float* s0    = partsb + 2*NTOK*DM;       // 512*256
  unsigned* flags = (unsigned*)(s0 + NTOK*DM);   // 4096 u32

  k_zero<<<1,512,0,stream>>>(flags);
  k_front<<<dim3(4,16),128,0,stream>>>(x, ep,ef,ed, plw,plb,piw,pib, fw,fb, s0);
  k_rln<<<NTOK,64,0,stream>>>(s0, tg, tb, feat);
  k_mega<<<256,512,0,stream>>>(ipw, cw, cb, xpw, dtw, dtb, alog, dpr, opw,
                               ng, nb, w1, b1, w2, b2,
                               feat, xcb, zsb, dtvb, Bmb, Cmb, ygb, partsb,
                               (float*)d_out, flags);
}

// Round 6
// 291.307 us; speedup vs baseline: 2.3124x; 1.0897x over previous
//
#include <hip/hip_runtime.h>
#include <cmath>

// BlockwiseEarlyExitMamba: output depends only on feat[:,31,:] -> compute T=32 tokens.
#define TT 32
#define NTOK 512   // BATCH*TT
#define DM 256
#define DI 512

typedef float vf4 __attribute__((ext_vector_type(4)));

__device__ __forceinline__ float silu_(float x){ return x / (1.f + __expf(-x)); }

// coherent store (LLC-level): global_store sc0 sc1, compiler-tracked (drained at syncthreads)
__device__ __forceinline__ void stc(float* p, float v){
  __hip_atomic_store(p, v, __ATOMIC_RELAXED, __HIP_MEMORY_SCOPE_AGENT);
}

// batched coherent loads: issue many, wait once; "+v" ties make consumers depend on the wait
#define GLD4(d, p) asm volatile("global_load_dwordx4 %0, %1, off sc0 sc1" : "=v"(d) : "v"(p))
#define AWAIT1(a)         asm volatile("s_waitcnt vmcnt(0)" : "+v"(a))
#define AWAIT2(a,b)       asm volatile("s_waitcnt vmcnt(0)" : "+v"(a), "+v"(b))
#define AWAIT4(a,b,c,d)   asm volatile("s_waitcnt vmcnt(0)" : "+v"(a), "+v"(b), "+v"(c), "+v"(d))
#define AWAIT8(a,b,c,d,e,f,g,h) asm volatile("s_waitcnt vmcnt(0)" : "+v"(a), "+v"(b), "+v"(c), "+v"(d), "+v"(e), "+v"(f), "+v"(g), "+v"(h))

#define FMA16() do { \
  acc[0][0] += xv.x*wv.x; acc[0][1] += xv.x*wv.y; acc[0][2] += xv.x*wv.z; acc[0][3] += xv.x*wv.w; \
  acc[1][0] += xv.y*wv.x; acc[1][1] += xv.y*wv.y; acc[1][2] += xv.y*wv.z; acc[1][3] += xv.y*wv.w; \
  acc[2][0] += xv.z*wv.x; acc[2][1] += xv.z*wv.y; acc[2][2] += xv.z*wv.z; acc[2][3] += xv.z*wv.w; \
  acc[3][0] += xv.w*wv.x; acc[3][1] += xv.w*wv.y; acc[3][2] += xv.w*wv.z; acc[3][3] += xv.w*wv.w; \
} while(0)

// ---- per-batch barrier (round-5, verified): fence-free, per-block flag lines ----
__device__ __forceinline__ void bbar(unsigned* flags, int b, int sub, unsigned e){
  __syncthreads();
  if (threadIdx.x == 0){
    asm volatile("s_waitcnt vmcnt(0)" ::: "memory");
    __hip_atomic_store(&flags[(b*16 + sub)*16], e, __ATOMIC_RELAXED, __HIP_MEMORY_SCOPE_AGENT);
  }
  if (threadIdx.x < 16){
    while (__hip_atomic_load(&flags[(b*16 + (int)threadIdx.x)*16], __ATOMIC_RELAXED,
                             __HIP_MEMORY_SCOPE_AGENT) < e)
      __builtin_amdgcn_s_sleep(2);
  }
  __syncthreads();
}

__global__ void k_zero(unsigned* f){
  for (int i = 0; i < 8; ++i) f[i*512 + threadIdx.x] = 0u;   // 4096 words
}

// ---------- frontend: embed -> fusion GEMM (K=136) -> raw s0 (verified) ------
__global__ __launch_bounds__(128)
void k_front(const float* __restrict__ x,
             const float* __restrict__ ep, const float* __restrict__ ef,
             const float* __restrict__ ed,
             const float* __restrict__ plw, const float* __restrict__ plb,
             const float* __restrict__ piw, const float* __restrict__ pib,
             const float* __restrict__ fw,  const float* __restrict__ fb,
             float* __restrict__ s0)
{
  __shared__ float Xs[136*36];
  __shared__ float Ws[136*68];
  int bb = blockIdx.y;
  int n0 = blockIdx.x*64;
  int tid = threadIdx.x;
  for (int r = 0; r < 34; ++r){
    int idx = r*128 + tid;
    int t = idx & 31, j = idx >> 5;
    const float* xr = x + ((size_t)(bb*1024 + t))*5;
    float v;
    if      (j <  32){ int i = __float2int_rz(xr[0]); i = min(max(i,0),255); v = ep[i*32 + j]; }
    else if (j <  64){ v = xr[1]*plw[j-32] + plb[j-32]; }
    else if (j <  96){ int i = __float2int_rz(xr[2]); i = min(max(i,0),63);  v = ef[i*32 + (j-64)]; }
    else if (j < 128){ v = xr[3]*piw[j-96] + pib[j-96]; }
    else             { int i = __float2int_rz(xr[4]); i = min(max(i,0),1);   v = ed[i*8 + (j-128)]; }
    Xs[j*36 + t] = v;
  }
  {
    int c = tid >> 1, jh = tid & 1;
    const float4* src = (const float4*)(fw + (size_t)(n0 + c)*136 + jh*68);
    #pragma unroll
    for (int q = 0; q < 17; ++q){
      float4 v = src[q];
      int j = jh*68 + q*4;
      Ws[(j+0)*68 + c] = v.x; Ws[(j+1)*68 + c] = v.y;
      Ws[(j+2)*68 + c] = v.z; Ws[(j+3)*68 + c] = v.w;
    }
  }
  __syncthreads();
  int my = tid >> 4, nx = tid & 15;
  float acc[4][4] = {};
  #pragma unroll 4
  for (int k = 0; k < 136; ++k){
    float4 xv = *(const float4*)&Xs[k*36 + my*4];
    float4 wv = *(const float4*)&Ws[k*68 + nx*4];
    FMA16();
  }
  #pragma unroll
  for (int i = 0; i < 4; ++i){
    int t = my*4 + i;
    float4 o;
    o.x = acc[i][0] + fb[n0 + nx*4 + 0];
    o.y = acc[i][1] + fb[n0 + nx*4 + 1];
    o.z = acc[i][2] + fb[n0 + nx*4 + 2];
    o.w = acc[i][3] + fb[n0 + nx*4 + 3];
    *(float4*)&s0[(size_t)(bb*32 + t)*DM + n0 + nx*4] = o;
  }
}

// ---------------- mega kernel: 4 layers + classifier, 16 per-batch barriers --
// bid = sub*16 + batch; dynamic LDS 102400 B; 1 block/CU (256 blocks resident)
__global__ __launch_bounds__(512, 1)
void k_mega(const float* __restrict__ ipw, const float* __restrict__ cw, const float* __restrict__ cb,
            const float* __restrict__ xpw, const float* __restrict__ dtw, const float* __restrict__ dtb,
            const float* __restrict__ alog, const float* __restrict__ dpr, const float* __restrict__ opw,
            const float* __restrict__ tg, const float* __restrict__ tb,
            const float* __restrict__ ng, const float* __restrict__ nb,
            const float* __restrict__ w1, const float* __restrict__ b1,
            const float* __restrict__ w2, const float* __restrict__ b2,
            const float* __restrict__ s0,
            float* __restrict__ xc, float* __restrict__ zs,
            float* __restrict__ dtv, float* __restrict__ Bm, float* __restrict__ Cm,
            float* __restrict__ yg, float* __restrict__ parts, float* __restrict__ out,
            unsigned* flags)
{
  extern __shared__ float lds[];   // [0,9216): featT [256][36] persistent; [9216,25600): scratch
  float* featT = lds;
  float* S = lds + 9216;
  int tid = threadIdx.x, bid = blockIdx.x;
  int b = bid & 15, sub = bid >> 4;
  int wvid = tid >> 6, ln = tid & 63;
  unsigned ep_ = 0;

  for (int ly = 0; ly < 4; ++ly){
    // ====== P1: [parts sum + residual + LN -> featT] + in_proj GEMM + conv ===
    {
      float* Wb  = S;           // 8192: W stage / acc reduce / LN partials
      float* sxz = S + 8192;    // 2176
      // ---- stage + residual + LN (replicated across the 16 sub-blocks) ----
      {
        int t = tid & 31, ci = tid >> 5;
        size_t base = (size_t)(b*32 + t)*DM + ci*16;
        const float* pA = (ly == 0) ? (s0 + base) : (parts + base);
        vf4 a0,a1,a2,a3;
        GLD4(a0, pA); GLD4(a1, pA+4); GLD4(a2, pA+8); GLD4(a3, pA+12);
        float v[16];
        if (ly){
          const float* pB = parts + 131072 + base;
          vf4 c0,c1,c2,c3;
          GLD4(c0, pB); GLD4(c1, pB+4); GLD4(c2, pB+8); GLD4(c3, pB+12);
          AWAIT8(a0,a1,a2,a3,c0,c1,c2,c3);
          #pragma unroll
          for (int j = 0; j < 4; ++j){
            v[j]    = a0[j]+c0[j]; v[4+j]  = a1[j]+c1[j];
            v[8+j]  = a2[j]+c2[j]; v[12+j] = a3[j]+c3[j];
          }
          #pragma unroll
          for (int j = 0; j < 16; ++j) v[j] += featT[(ci*16+j)*36 + t];   // residual
        } else {
          AWAIT4(a0,a1,a2,a3);
          #pragma unroll
          for (int j = 0; j < 4; ++j){
            v[j] = a0[j]; v[4+j] = a1[j]; v[8+j] = a2[j]; v[12+j] = a3[j];
          }
        }
        float s = 0.f, sq = 0.f;
        #pragma unroll
        for (int j = 0; j < 16; ++j){ s += v[j]; sq += v[j]*v[j]; }
        float* redS = Wb; float* redQ = Wb + 544;
        redS[t*17 + ci] = s; redQ[t*17 + ci] = sq;
        __syncthreads();
        float Ssum = 0.f, Qsum = 0.f;
        #pragma unroll
        for (int k2 = 0; k2 < 16; ++k2){ Ssum += redS[t*17+k2]; Qsum += redQ[t*17+k2]; }
        float mu = Ssum*(1.f/256.f), var = Qsum*(1.f/256.f) - mu*mu;
        float r = rsqrtf(var + 1e-5f);
        const float* g  = ly ? ng : tg;
        const float* bb2 = ly ? nb : tb;
        #pragma unroll
        for (int j = 0; j < 16; ++j){
          int c = ci*16 + j;
          featT[c*36 + t] = (v[j]-mu)*r*g[c] + bb2[c];
        }
      }
      // ---- GEMM (wave-split-K, W staged+swizzled; X from featT) ----
      int n0 = sub*64;
      const float* wip = ipw + (size_t)ly*262144;
      float acc[8][4] = {};
      int ty = ln >> 4, nx = ln & 15;
      int swz = wvid << 2;
      for (int cc = 0; cc < 2; ++cc){
        __syncthreads();
        {
          int n = tid >> 3, kh = tid & 7;
          const float4* src = (const float4*)(wip + (size_t)(n0+n)*DM + cc*128 + kh*16);
          int nn = n ^ ((kh & 7) << 2);
          #pragma unroll
          for (int q = 0; q < 4; ++q){
            float4 v = src[q];
            int kl = kh*16 + q*4;
            Wb[(kl+0)*64 + nn] = v.x; Wb[(kl+1)*64 + nn] = v.y;
            Wb[(kl+2)*64 + nn] = v.z; Wb[(kl+3)*64 + nn] = v.w;
          }
        }
        __syncthreads();
        #pragma unroll
        for (int kk = 0; kk < 16; ++kk){
          int kl = wvid*16 + kk;
          int kg = cc*128 + kl;
          vf4 x0 = *(const vf4*)&featT[kg*36 + ty*8];
          vf4 x1 = *(const vf4*)&featT[kg*36 + ty*8 + 4];
          vf4 wv = *(const vf4*)&Wb[kl*64 + ((nx*4) ^ swz)];
          #pragma unroll
          for (int i = 0; i < 4; ++i){
            #pragma unroll
            for (int j = 0; j < 4; ++j){
              acc[i][j]   += x0[i]*wv[j];
              acc[i+4][j] += x1[i]*wv[j];
            }
          }
        }
      }
      float* P = Wb;
      for (int s2 = 4; s2 >= 1; s2 >>= 1){
        __syncthreads();
        if (wvid >= s2 && wvid < 2*s2){
          float* dst = P + (wvid - s2)*2048;
          #pragma unroll
          for (int i = 0; i < 8; ++i) *(vf4*)&dst[i*256 + ln*4] = *(vf4*)&acc[i][0];
        }
        __syncthreads();
        if (wvid < s2){
          const float* sp = P + wvid*2048;
          #pragma unroll
          for (int i = 0; i < 8; ++i){
            vf4 v = *(const vf4*)&sp[i*256 + ln*4];
            acc[i][0]+=v[0]; acc[i][1]+=v[1]; acc[i][2]+=v[2]; acc[i][3]+=v[3];
          }
        }
      }
      __syncthreads();
      if (wvid == 0){
        #pragma unroll
        for (int i = 0; i < 8; ++i){
          int t = ty*8 + i;
          *(vf4*)&sxz[t*68 + nx*4] = *(vf4*)&acc[i][0];
        }
      }
      __syncthreads();
      { // conv+silu (x-slices) or silu (z-slices)
        int t = tid >> 4, nn = (tid & 15)*4;
        int p = b*32 + t;
        float rr[4];
        if (n0 < 512){
          const float* cwl = cw + (size_t)ly*2048;
          const float* cbl = cb + (size_t)ly*512;
          #pragma unroll
          for (int j = 0; j < 4; ++j){
            int d = n0 + nn + j;
            float4 k4 = *(const float4*)(cwl + (size_t)d*4);
            float a = cbl[d];
            if (t >= 3) a += k4.x * sxz[(t-3)*68 + nn + j];
            if (t >= 2) a += k4.y * sxz[(t-2)*68 + nn + j];
            if (t >= 1) a += k4.z * sxz[(t-1)*68 + nn + j];
            a += k4.w * sxz[t*68 + nn + j];
            rr[j] = silu_(a);
          }
          size_t xo = (size_t)p*DI + n0 + nn;
          stc(&xc[xo+0], rr[0]); stc(&xc[xo+1], rr[1]);
          stc(&xc[xo+2], rr[2]); stc(&xc[xo+3], rr[3]);
        } else {
          int dz = n0 - 512 + nn;
          #pragma unroll
          for (int j = 0; j < 4; ++j) rr[j] = silu_(sxz[t*68 + nn + j]);
          size_t zo = (size_t)p*DI + dz;
          stc(&zs[zo+0], rr[0]); stc(&zs[zo+1], rr[1]);
          stc(&zs[zo+2], rr[2]); stc(&zs[zo+3], rr[3]);
        }
      }
    }
    bbar(flags, b, sub, ++ep_);

    // ====== XP: x_proj (8 waves x 6 ch, 2 tokens) + dt softplus ==============
    {
      float* sxc = S;            // 1024
      float* sdtr = S + 1024;    // 32
      int p0 = b*32 + sub*2;
      if (tid < 256){
        int h = tid >> 7, i = (tid & 127)*4;
        vf4 u; GLD4(u, xc + (size_t)(p0+h)*DI + i); AWAIT1(u);
        *(vf4*)&sxc[h*512 + i] = u;
      }
      __syncthreads();
      const float* xpl = xpw + (size_t)ly*48*512;
      #pragma unroll
      for (int j = 0; j < 6; ++j){
        int c = wvid*6 + j;
        const float* wr = xpl + (size_t)c*512;
        float pa = 0.f, pb = 0.f;
        #pragma unroll
        for (int q = 0; q < 8; ++q){
          float wv = wr[ln + 64*q];
          pa += wv * sxc[ln + 64*q];
          pb += wv * sxc[512 + ln + 64*q];
        }
        #pragma unroll
        for (int o = 32; o; o >>= 1){ pa += __shfl_down(pa, o, 64); pb += __shfl_down(pb, o, 64); }
        if (ln == 0){
          if (c < 16){ sdtr[c] = pa; sdtr[16 + c] = pb; }
          else if (c < 32){ stc(&Bm[(size_t)p0*16 + (c-16)], pa); stc(&Bm[(size_t)(p0+1)*16 + (c-16)], pb); }
          else            { stc(&Cm[(size_t)p0*16 + (c-32)], pa); stc(&Cm[(size_t)(p0+1)*16 + (c-32)], pb); }
        }
      }
      __syncthreads();
      {
        int d = tid;
        const float4* dwr = (const float4*)(dtw + (size_t)ly*8192 + (size_t)d*16);
        float4 a0 = dwr[0], a1 = dwr[1], a2 = dwr[2], a3 = dwr[3];
        float bsv = dtb[ly*512 + d];
        #pragma unroll
        for (int h = 0; h < 2; ++h){
          const float* sr = sdtr + h*16;
          float a = bsv;
          a += a0.x*sr[0] + a0.y*sr[1] + a0.z*sr[2] + a0.w*sr[3];
          a += a1.x*sr[4] + a1.y*sr[5] + a1.z*sr[6] + a1.w*sr[7];
          a += a2.x*sr[8] + a2.y*sr[9] + a2.z*sr[10]+ a2.w*sr[11];
          a += a3.x*sr[12]+ a3.y*sr[13]+ a3.z*sr[14]+ a3.w*sr[15];
          stc(&dtv[(size_t)(p0+h)*DI + d], fmaxf(a, 0.f) + log1pf(expf(-fabsf(a))));
        }
      }
    }
    bbar(flags, b, sub, ++ep_);

    // ====== SC: selective scan (d,n parallel) + D-skip + gate ================
    {
      float* sdt = S;            // [32][36]
      float* sxv = S + 1152;
      float* szz = S + 2304;
      float* sB  = S + 3456;     // [32][20]
      float* sC  = S + 4096;
      int d0 = sub*32;
      if (tid < 256){
        int t = tid >> 3, q = (tid & 7)*4;
        size_t base = (size_t)(b*32 + t)*DI + d0 + q;
        vf4 u, w; GLD4(u, dtv + base); GLD4(w, zs + base); AWAIT2(u, w);
        *(vf4*)&sdt[t*36 + q] = u;
        *(vf4*)&szz[t*36 + q] = w;
      } else {
        int u2 = tid - 256;
        int t = u2 >> 3, q = (u2 & 7)*4;
        size_t base = (size_t)(b*32 + t)*DI + d0 + q;
        vf4 u; GLD4(u, xc + base);
        int t2, n4; const float* pbc;
        if (u2 < 128){ t2 = u2 >> 2; n4 = (u2 & 3)*4; pbc = Bm + (size_t)(b*32+t2)*16 + n4; }
        else { int u3 = u2 - 128; t2 = u3 >> 2; n4 = (u3 & 3)*4; pbc = Cm + (size_t)(b*32+t2)*16 + n4; }
        vf4 w; GLD4(w, pbc); AWAIT2(u, w);
        *(vf4*)&sxv[t*36 + q] = u;
        if (u2 < 128) *(vf4*)&sB[t2*20 + n4] = w; else *(vf4*)&sC[t2*20 + n4] = w;
      }
      __syncthreads();
      int dd = tid >> 4, nidx = tid & 15;
      int d = d0 + dd;
      float A = -expf(alog[(size_t)ly*8192 + (size_t)d*16 + nidx]);
      float Dp = dpr[ly*512 + d];
      float h = 0.f;
      #pragma unroll 4
      for (int t = 0; t < TT; ++t){
        float dt = sdt[t*36 + dd];
        float xv = sxv[t*36 + dd];
        h = __expf(dt*A)*h + (dt*xv)*sB[t*20 + nidx];
        float yv = h * sC[t*20 + nidx];
        #pragma unroll
        for (int o = 8; o; o >>= 1) yv += __shfl_xor(yv, o, 64);
        if (nidx == 0){
          float yo = (yv + Dp*xv) * szz[t*36 + dd];
          stc(&yg[(size_t)(b*32+t)*DI + d], yo);
        }
      }
    }
    bbar(flags, b, sub, ++ep_);

    // ====== OP: out_proj GEMM (2-way split-K, wave-split) ====================
    {
      float* Xs = S;             // 8192
      float* W  = S + 8192;      // 8192 (also reduce region)
      int ns = sub >> 1, kz = sub & 1;
      int m0 = b*32, n0 = ns*32, k0 = kz*256;
      const float* wop = opw + (size_t)ly*131072;
      {
        int t = tid >> 4, kq = tid & 15;
        const float* src = yg + (size_t)(m0+t)*DI + k0 + kq*16;
        vf4 u0,u1,u2,u3;
        GLD4(u0, src); GLD4(u1, src+4); GLD4(u2, src+8); GLD4(u3, src+12);
        AWAIT4(u0,u1,u2,u3);
        int tt = t ^ ((kq & 7) << 2);
        int k = kq*16;
        #pragma unroll
        for (int j = 0; j < 4; ++j) Xs[(k+j)*32 + tt]    = u0[j];
        #pragma unroll
        for (int j = 0; j < 4; ++j) Xs[(k+4+j)*32 + tt]  = u1[j];
        #pragma unroll
        for (int j = 0; j < 4; ++j) Xs[(k+8+j)*32 + tt]  = u2[j];
        #pragma unroll
        for (int j = 0; j < 4; ++j) Xs[(k+12+j)*32 + tt] = u3[j];
      }
      {
        int n = tid >> 4, kh = tid & 15;
        const float4* src = (const float4*)(wop + (size_t)(n0+n)*DI + k0 + kh*16);
        int nn = n ^ ((kh & 7) << 2);
        #pragma unroll
        for (int q = 0; q < 4; ++q){
          float4 v = src[q];
          int k = kh*16 + q*4;
          W[(k+0)*32 + nn] = v.x; W[(k+1)*32 + nn] = v.y;
          W[(k+2)*32 + nn] = v.z; W[(k+3)*32 + nn] = v.w;
        }
      }
      __syncthreads();
      int ty = ln >> 3, nx = ln & 7;
      float acc[4][4] = {};
      #pragma unroll
      for (int kk = 0; kk < 32; ++kk){
        int k = wvid*32 + kk;
        int swz2 = ((k >> 4) & 7) << 2;
        vf4 xv = *(const vf4*)&Xs[k*32 + ((ty*4) ^ swz2)];
        vf4 wv = *(const vf4*)&W[k*32 + ((nx*4) ^ swz2)];
        #pragma unroll
        for (int i = 0; i < 4; ++i){
          #pragma unroll
          for (int j = 0; j < 4; ++j) acc[i][j] += xv[i]*wv[j];
        }
      }
      float* P = W;
      for (int s2 = 4; s2 >= 1; s2 >>= 1){
        __syncthreads();
        if (wvid >= s2 && wvid < 2*s2){
          float* dst = P + (wvid - s2)*1024;
          #pragma unroll
          for (int i = 0; i < 4; ++i) *(vf4*)&dst[i*256 + ln*4] = *(vf4*)&acc[i][0];
        }
        __syncthreads();
        if (wvid < s2){
          const float* sp = P + wvid*1024;
          #pragma unroll
          for (int i = 0; i < 4; ++i){
            vf4 v = *(const vf4*)&sp[i*256 + ln*4];
            acc[i][0]+=v[0]; acc[i][1]+=v[1]; acc[i][2]+=v[2]; acc[i][3]+=v[3];
          }
        }
      }
      if (wvid == 0){
        #pragma unroll
        for (int i = 0; i < 4; ++i){
          size_t po = (size_t)kz*131072 + (size_t)(m0 + ty*4 + i)*DM + n0 + nx*4;
          stc(&parts[po+0], acc[i][0]); stc(&parts[po+1], acc[i][1]);
          stc(&parts[po+2], acc[i][2]); stc(&parts[po+3], acc[i][3]);
        }
      }
    }
    bbar(flags, b, sub, ++ep_);
  } // layers

  // ====== CLS: final residual+LN for token 31 (from LDS featT) + classifier ==
  if (sub == 0){
    float* h  = S;
    float* h1 = S + 256;
    if (tid < 64){
      int c4 = tid*4;
      size_t base = (size_t)(b*32 + 31)*DM + c4;
      vf4 u, w;
      GLD4(u, parts + base); GLD4(w, parts + 131072 + base); AWAIT2(u, w);
      float v4[4]; float s = 0.f, sq = 0.f;
      #pragma unroll
      for (int j = 0; j < 4; ++j){
        v4[j] = u[j] + w[j] + featT[(c4+j)*36 + 31];
        s += v4[j]; sq += v4[j]*v4[j];
      }
      #pragma unroll
      for (int o = 1; o < 64; o <<= 1){ s += __shfl_xor(s, o, 64); sq += __shfl_xor(sq, o, 64); }
      float mu = s*(1.f/256.f), var = sq*(1.f/256.f) - mu*mu;
      float r = rsqrtf(var + 1e-5f);
      #pragma unroll
      for (int j = 0; j < 4; ++j) h[c4+j] = (v4[j]-mu)*r*ng[c4+j] + nb[c4+j];
    }
    __syncthreads();
    if (tid < 128){
      float a = b1[tid];
      const float* wr = w1 + (size_t)tid*256;
      #pragma unroll 8
      for (int j = 0; j < 256; ++j) a += h[j]*wr[j];
      h1[tid] = fmaxf(a, 0.f);
    }
    __syncthreads();
    if (tid < 2){
      float a2 = b2[tid];
      const float* wr2 = w2 + (size_t)tid*128;
      #pragma unroll 8
      for (int j = 0; j < 128; ++j) a2 += h1[j]*wr2[j];
      out[b*2 + tid] = a2;
    }
  }
}

extern "C" void kernel_launch(void* const* d_in, const int* in_sizes, int n_in,
                              void* d_out, int out_size, void* d_ws, size_t ws_size,
                              hipStream_t stream)
{
  const float* x   = (const float*)d_in[0];
  const float* ep  = (const float*)d_in[1];
  const float* ef  = (const float*)d_in[2];
  const float* ed  = (const float*)d_in[3];
  const float* plw = (const float*)d_in[4];
  const float* plb = (const float*)d_in[5];
  const float* piw = (const float*)d_in[6];
  const float* pib = (const float*)d_in[7];
  const float* fw  = (const float*)d_in[8];
  const float* fb  = (const float*)d_in[9];
  const float* tg  = (const float*)d_in[10];
  const float* tb  = (const float*)d_in[11];
  const float* ng  = (const float*)d_in[12];
  const float* nb  = (const float*)d_in[13];
  const float* ipw = (const float*)d_in[14];
  const float* cw  = (const float*)d_in[15];
  const float* cb  = (const float*)d_in[16];
  const float* xpw = (const float*)d_in[17];
  const float* dtw = (const float*)d_in[18];
  const float* dtb = (const float*)d_in[19];
  const float* alog= (const float*)d_in[20];
  const float* dpr = (const float*)d_in[21];
  const float* opw = (const float*)d_in[22];
  const float* w1  = (const float*)d_in[23];
  const float* b1  = (const float*)d_in[24];
  const float* w2  = (const float*)d_in[25];
  const float* b2  = (const float*)d_in[26];
  (void)in_sizes; (void)n_in; (void)out_size; (void)ws_size;

  float* ws    = (float*)d_ws;
  float* xcb   = ws;                       // 512*512
  float* zsb   = xcb  + NTOK*DI;           // 512*512
  float* dtvb  = zsb  + NTOK*DI;           // 512*512
  float* ygb   = dtvb + NTOK*DI;           // 512*512
  float* Bmb   = ygb  + NTOK*DI;           // 512*16
  float* Cmb   = Bmb  + NTOK*16;           // 512*16
  float* partsb= Cmb  + NTOK*16;           // 2*512*256
  float* s0    = partsb + 2*NTOK*DM;       // 512*256
  unsigned* flags = (unsigned*)(s0 + NTOK*DM);   // 4096 u32

  k_zero<<<1,512,0,stream>>>(flags);
  k_front<<<dim3(4,16),128,0,stream>>>(x, ep,ef,ed, plw,plb,piw,pib, fw,fb, s0);
  k_mega<<<256,512,102400,stream>>>(ipw, cw, cb, xpw, dtw, dtb, alog, dpr, opw,
                                    tg, tb, ng, nb, w1, b1, w2, b2, s0,
                                    xcb, zsb, dtvb, Bmb, Cmb, ygb, partsb,
                                    (float*)d_out, flags);
}